// Round 1
// baseline (1421.216 us; speedup 1.0000x reference)
//
#include <hip/hip_runtime.h>

// ---------- helpers ----------
__device__ __forceinline__ unsigned short f2bf(float f) {
  unsigned u = __builtin_bit_cast(unsigned, f);
  u = u + 0x7fffu + ((u >> 16) & 1u);      // RNE
  return (unsigned short)(u >> 16);
}
__device__ __forceinline__ float bf2f(unsigned short u) {
  return __builtin_bit_cast(float, ((unsigned)u) << 16);
}

typedef __bf16 bf16x8 __attribute__((ext_vector_type(8)));
typedef float  f32x4  __attribute__((ext_vector_type(4)));

// ---------- rmsnorm (+ optional residual) ----------
// xin[row][1024] (+delta) -> xsum(f32, opt), nbf(bf16), nf32(f32, opt)
template<int HAS_DELTA, int WRITE_SUM, int WRITE_N32>
__global__ __launch_bounds__(256) void resrms_k(const float* __restrict__ xin,
    const float* __restrict__ delta, float* __restrict__ xsum,
    unsigned short* __restrict__ nbf, float* __restrict__ nf32) {
  int row = blockIdx.x, tid = threadIdx.x;
  size_t base = ((size_t)row << 10) + ((size_t)tid << 2);
  float4 v = *(const float4*)(xin + base);
  if (HAS_DELTA) {
    float4 d = *(const float4*)(delta + base);
    v.x += d.x; v.y += d.y; v.z += d.z; v.w += d.w;
  }
  if (WRITE_SUM) *(float4*)(xsum + base) = v;
  float ss = v.x*v.x + v.y*v.y + v.z*v.z + v.w*v.w;
  #pragma unroll
  for (int off = 32; off; off >>= 1) ss += __shfl_xor(ss, off);
  __shared__ float ws4[4];
  if ((tid & 63) == 0) ws4[tid >> 6] = ss;
  __syncthreads();
  float tot = ws4[0] + ws4[1] + ws4[2] + ws4[3];
  float sc = rsqrtf(tot * (1.0f / 1024.0f) + 1e-5f);
  *(ushort4*)(nbf + base) = make_ushort4(f2bf(v.x*sc), f2bf(v.y*sc), f2bf(v.z*sc), f2bf(v.w*sc));
  if (WRITE_N32) {
    float4 n; n.x = v.x*sc; n.y = v.y*sc; n.z = v.z*sc; n.w = v.w*sc;
    *(float4*)(nf32 + base) = n;
  }
}

// ---------- transpose+convert: W[K][ldw] f32 (cols col_off..col_off+Ncols) -> Wt[Npad][K] bf16 ----------
__global__ void transp_k(const float* __restrict__ W, unsigned short* __restrict__ Wt,
                         int K, int Ncols, int Npad, int col_off, int ldw) {
  __shared__ float t[32][33];
  int n0 = blockIdx.x << 5, k0 = blockIdx.y << 5;
  int tx = threadIdx.x, ty = threadIdx.y;
  #pragma unroll
  for (int rr = 0; rr < 32; rr += 8) {
    int k = k0 + rr + ty, n = n0 + tx;
    t[rr + ty][tx] = (n < Ncols) ? W[(size_t)k * ldw + col_off + n] : 0.f;
  }
  __syncthreads();
  #pragma unroll
  for (int rr = 0; rr < 32; rr += 8) {
    int nrow = n0 + rr + ty;
    Wt[(size_t)nrow * K + k0 + tx] = f2bf(t[tx][rr + ty]);
  }
}

// ---------- bf16 MFMA GEMM: C[M][N] = A[M][K] * Bt[N][K]^T ----------
// EPI: 0 = f32 store, 1 = bf16 store, 2 = erf-activation -> bf16 store
template<int EPI>
__global__ __launch_bounds__(256) void gemm_k(const unsigned short* __restrict__ A,
    const unsigned short* __restrict__ Bt, void* __restrict__ Cout,
    int M, int N, int K) {
  __shared__ unsigned short As[128][40];
  __shared__ unsigned short Bs[128][40];
  int tid = threadIdx.x;
  int wave = tid >> 6, lane = tid & 63;
  int m0 = blockIdx.y << 7, n0 = blockIdx.x << 7;
  int wm = (wave >> 1) << 6, wn = (wave & 1) << 6;
  int fr = lane & 15, g = lane >> 4;
  f32x4 acc[4][4];
  #pragma unroll
  for (int i = 0; i < 4; ++i)
    #pragma unroll
    for (int j = 0; j < 4; ++j) acc[i][j] = (f32x4){0.f, 0.f, 0.f, 0.f};
  const unsigned short* Ap = A + (size_t)m0 * K;
  const unsigned short* Bp = Bt + (size_t)n0 * K;
  for (int k0 = 0; k0 < K; k0 += 32) {
    __syncthreads();
    #pragma unroll
    for (int pass = 0; pass < 2; ++pass) {
      int c = tid + (pass << 8);
      int r = c >> 2, kp = (c & 3) << 3;
      *(uint4*)&As[r][kp] = *(const uint4*)(Ap + (size_t)r * K + k0 + kp);
      *(uint4*)&Bs[r][kp] = *(const uint4*)(Bp + (size_t)r * K + k0 + kp);
    }
    __syncthreads();
    bf16x8 af[4], bv[4];
    #pragma unroll
    for (int i = 0; i < 4; ++i) af[i] = *(const bf16x8*)&As[wm + (i << 4) + fr][g << 3];
    #pragma unroll
    for (int j = 0; j < 4; ++j) bv[j] = *(const bf16x8*)&Bs[wn + (j << 4) + fr][g << 3];
    #pragma unroll
    for (int i = 0; i < 4; ++i)
      #pragma unroll
      for (int j = 0; j < 4; ++j)
        acc[i][j] = __builtin_amdgcn_mfma_f32_16x16x32_bf16(af[i], bv[j], acc[i][j], 0, 0, 0);
  }
  int rin = g << 2;
  #pragma unroll
  for (int i = 0; i < 4; ++i) {
    #pragma unroll
    for (int j = 0; j < 4; ++j) {
      int col = n0 + wn + (j << 4) + fr;
      if (col < N) {
        #pragma unroll
        for (int rr = 0; rr < 4; ++rr) {
          int row = m0 + wm + (i << 4) + rin + rr;
          float v = acc[i][j][rr];
          if (EPI == 0) {
            ((float*)Cout)[(size_t)row * N + col] = v;
          } else if (EPI == 1) {
            ((unsigned short*)Cout)[(size_t)row * N + col] = f2bf(v);
          } else {
            float kv = 0.5f * (1.0f + erff((v - 0.70710678f) * 2.5066283f));
            ((unsigned short*)Cout)[(size_t)row * N + col] = f2bf(kv);
          }
        }
      }
    }
  }
}

// ---------- dt / dA ----------
__global__ __launch_bounds__(256) void dtk(const float* __restrict__ zxr,
    const float* __restrict__ dt_bias, const float* __restrict__ A_log,
    float* __restrict__ dt, float* __restrict__ dA) {
  int i = blockIdx.x * 256 + threadIdx.x;     // 4096*32
  int r = i >> 5, hh = i & 31;
  float v = zxr[(size_t)r * 2208 + 2176 + hh] + dt_bias[hh];
  float dtv = (v > 20.f) ? v : log1pf(__expf(v));
  float Ah = -__expf(A_log[hh]);
  dt[i] = dtv;
  dA[i] = __expf(dtv * Ah);
}

// ---------- causal depthwise conv(4) + silu ----------
__global__ __launch_bounds__(256) void convk(const float* __restrict__ zxr,
    const float* __restrict__ conv_w, const float* __restrict__ conv_b,
    float* __restrict__ xbc) {
  int i = blockIdx.x * 256 + threadIdx.x;     // 4*1024*2176
  if (i >= 4 * 1024 * 2176) return;
  int c = i % 2176; int bt = i / 2176; int t = bt & 1023;
  const float* col = zxr + (size_t)bt * 2208 + c;
  float acc = conv_b[c];
  float w0 = conv_w[c * 4 + 0], w1 = conv_w[c * 4 + 1], w2 = conv_w[c * 4 + 2], w3 = conv_w[c * 4 + 3];
  if (t >= 3) acc = fmaf(col[-3 * 2208], w0, acc);
  if (t >= 2) acc = fmaf(col[-2 * 2208], w1, acc);
  if (t >= 1) acc = fmaf(col[-1 * 2208], w2, acc);
  acc = fmaf(col[0], w3, acc);
  xbc[(size_t)bt * 2176 + c] = acc / (1.f + __expf(-acc));
}

// ---------- sequential SSM scan: ydin = scan + D*xs ----------
__global__ __launch_bounds__(256) void scank(const float* __restrict__ xbc,
    const float* __restrict__ dtv, const float* __restrict__ dav,
    const float* __restrict__ Dv, float* __restrict__ ydin) {
  const int bid = blockIdx.x;                 // 256 = b(4) * h(32) * ph(2)
  const int ph = bid & 1, h = (bid >> 1) & 31, b = bid >> 6;
  const int tid = threadIdx.x;
  const int p = (ph << 5) + (tid >> 3), n0 = (tid & 7) << 3;
  float hr[8] = {0, 0, 0, 0, 0, 0, 0, 0};
  const float Dh = Dv[h];
  const float* xb = xbc + ((size_t)(b << 10)) * 2176;
  const float* dtb = dtv + (((size_t)(b << 10)) << 5) + h;
  const float* dab = dav + (((size_t)(b << 10)) << 5) + h;
  float* yb = ydin + (((size_t)(b << 10)) << 11) + (h << 6) + p;
  const int xoff = (h << 6) + p;

#define DECLP(s) float x##s, dq##s, da##s; float4 B0##s, B1##s, C0##s, C1##s;
#define LOADP(s, tt) { const float* row_ = xb + (size_t)(tt) * 2176; \
    x##s = row_[xoff]; dq##s = dtb[(tt) << 5]; da##s = dab[(tt) << 5]; \
    B0##s = *(const float4*)(row_ + 2048 + n0); B1##s = *(const float4*)(row_ + 2052 + n0); \
    C0##s = *(const float4*)(row_ + 2112 + n0); C1##s = *(const float4*)(row_ + 2116 + n0); }
#define STEPP(s, tt) { float cm_ = dq##s * x##s; float pt_; \
    hr[0] = fmaf(da##s, hr[0], cm_ * B0##s.x); pt_  = hr[0] * C0##s.x; \
    hr[1] = fmaf(da##s, hr[1], cm_ * B0##s.y); pt_ += hr[1] * C0##s.y; \
    hr[2] = fmaf(da##s, hr[2], cm_ * B0##s.z); pt_ += hr[2] * C0##s.z; \
    hr[3] = fmaf(da##s, hr[3], cm_ * B0##s.w); pt_ += hr[3] * C0##s.w; \
    hr[4] = fmaf(da##s, hr[4], cm_ * B1##s.x); pt_ += hr[4] * C1##s.x; \
    hr[5] = fmaf(da##s, hr[5], cm_ * B1##s.y); pt_ += hr[5] * C1##s.y; \
    hr[6] = fmaf(da##s, hr[6], cm_ * B1##s.z); pt_ += hr[6] * C1##s.z; \
    hr[7] = fmaf(da##s, hr[7], cm_ * B1##s.w); pt_ += hr[7] * C1##s.w; \
    pt_ += __shfl_xor(pt_, 1); pt_ += __shfl_xor(pt_, 2); pt_ += __shfl_xor(pt_, 4); \
    if ((tid & 7) == 0) yb[(size_t)(tt) << 11] = fmaf(Dh, x##s, pt_); }

  DECLP(0) DECLP(1) DECLP(2) DECLP(3)
  LOADP(0, 0) LOADP(1, 1) LOADP(2, 2) LOADP(3, 3)
  int t = 0;
  for (; t < 1020; t += 4) {
    STEPP(0, t)     LOADP(0, t + 4)
    STEPP(1, t + 1) LOADP(1, t + 5)
    STEPP(2, t + 2) LOADP(2, t + 6)
    STEPP(3, t + 3) LOADP(3, t + 7)
  }
  STEPP(0, 1020) STEPP(1, 1021) STEPP(2, 1022) STEPP(3, 1023)
#undef DECLP
#undef LOADP
#undef STEPP
}

// ---------- g = ydin * silu(z); rmsnorm(2048) * mnorm_w -> bf16 ----------
__global__ __launch_bounds__(256) void gnormk(const float* __restrict__ ydin,
    const unsigned short* __restrict__ zbf, const float* __restrict__ mw,
    unsigned short* __restrict__ gbf) {
  int row = blockIdx.x, tid = threadIdx.x;
  size_t base = ((size_t)row << 11) + ((size_t)tid << 3);
  float4 y0 = *(const float4*)(ydin + base);
  float4 y1 = *(const float4*)(ydin + base + 4);
  ushort4 z0 = *(const ushort4*)(zbf + base);
  ushort4 z1 = *(const ushort4*)(zbf + base + 4);
  float g[8];
  {
    float z;
    z = bf2f(z0.x); g[0] = y0.x * (z / (1.f + __expf(-z)));
    z = bf2f(z0.y); g[1] = y0.y * (z / (1.f + __expf(-z)));
    z = bf2f(z0.z); g[2] = y0.z * (z / (1.f + __expf(-z)));
    z = bf2f(z0.w); g[3] = y0.w * (z / (1.f + __expf(-z)));
    z = bf2f(z1.x); g[4] = y1.x * (z / (1.f + __expf(-z)));
    z = bf2f(z1.y); g[5] = y1.y * (z / (1.f + __expf(-z)));
    z = bf2f(z1.z); g[6] = y1.z * (z / (1.f + __expf(-z)));
    z = bf2f(z1.w); g[7] = y1.w * (z / (1.f + __expf(-z)));
  }
  float ss = 0.f;
  #pragma unroll
  for (int k = 0; k < 8; ++k) ss += g[k] * g[k];
  #pragma unroll
  for (int off = 32; off; off >>= 1) ss += __shfl_xor(ss, off);
  __shared__ float ws4[4];
  if ((tid & 63) == 0) ws4[tid >> 6] = ss;
  __syncthreads();
  float tot = ws4[0] + ws4[1] + ws4[2] + ws4[3];
  float sc = rsqrtf(tot * (1.f / 2048.f) + 1e-5f);
  int c0 = tid << 3;
  float4 m0 = *(const float4*)(mw + c0);
  float4 m1 = *(const float4*)(mw + c0 + 4);
  *(ushort4*)(gbf + base)     = make_ushort4(f2bf(g[0]*sc*m0.x), f2bf(g[1]*sc*m0.y), f2bf(g[2]*sc*m0.z), f2bf(g[3]*sc*m0.w));
  *(ushort4*)(gbf + base + 4) = make_ushort4(f2bf(g[4]*sc*m1.x), f2bf(g[5]*sc*m1.y), f2bf(g[6]*sc*m1.z), f2bf(g[7]*sc*m1.w));
}

// ---------- MQA causal attention (vector flash), out bf16 ----------
__global__ __launch_bounds__(256) void attnk(const float* __restrict__ qkv,
                                             unsigned short* __restrict__ ybf) {
  const int b = blockIdx.z, hh = blockIdx.y, qt = blockIdx.x;
  const int t0 = qt << 5;
  __shared__ float Qs[32][64];
  __shared__ float Ks[64][65];
  __shared__ float Vst[64][65];
  const int tid = threadIdx.x, w = tid >> 6, lane = tid & 63;
  {
    int r = tid >> 3, dc = (tid & 7) << 3;
    const float* src = qkv + ((size_t)((b << 10) | (t0 + r))) * 1152 + (hh << 6) + dc;
    float4 a = *(const float4*)src;
    float4 c = *(const float4*)(src + 4);
    float* q = &Qs[r][dc];
    q[0] = a.x * 0.125f; q[1] = a.y * 0.125f; q[2] = a.z * 0.125f; q[3] = a.w * 0.125f;
    q[4] = c.x * 0.125f; q[5] = c.y * 0.125f; q[6] = c.z * 0.125f; q[7] = c.w * 0.125f;
  }
  float mrow[8], lrow[8], acc[8];
  #pragma unroll
  for (int i = 0; i < 8; ++i) { mrow[i] = -1e30f; lrow[i] = 0.f; acc[i] = 0.f; }
  const int r0 = w << 3;
  const int ntile = (t0 + 95) >> 6;
  for (int kt = 0; kt < ntile; ++kt) {
    const int s0 = kt << 6;
    __syncthreads();
    {
      int r = tid >> 2, f0 = (tid & 3) << 4;
      const float* kr = qkv + ((size_t)((b << 10) | (s0 + r))) * 1152 + 1024;
      #pragma unroll
      for (int u = 0; u < 4; ++u) {
        int d0 = f0 + (u << 2);
        float4 kk = *(const float4*)(kr + d0);
        float4 vv = *(const float4*)(kr + 64 + d0);
        Ks[r][d0 + 0] = kk.x; Ks[r][d0 + 1] = kk.y; Ks[r][d0 + 2] = kk.z; Ks[r][d0 + 3] = kk.w;
        Vst[d0 + 0][r] = vv.x; Vst[d0 + 1][r] = vv.y; Vst[d0 + 2][r] = vv.z; Vst[d0 + 3][r] = vv.w;
      }
    }
    __syncthreads();
    const int sp = s0 + lane;
    #pragma unroll
    for (int ii = 0; ii < 8; ii += 2) {
      const int tq0 = t0 + r0 + ii, tq1 = tq0 + 1;
      float sc0 = 0.f, sc1 = 0.f;
      const float4* q0 = (const float4*)(&Qs[r0 + ii][0]);
      const float4* q1 = (const float4*)(&Qs[r0 + ii + 1][0]);
      #pragma unroll
      for (int d4 = 0; d4 < 16; ++d4) {
        float4 qa = q0[d4], qb = q1[d4];
        float k0v = Ks[lane][(d4 << 2) + 0], k1v = Ks[lane][(d4 << 2) + 1];
        float k2v = Ks[lane][(d4 << 2) + 2], k3v = Ks[lane][(d4 << 2) + 3];
        sc0 = fmaf(qa.x, k0v, fmaf(qa.y, k1v, fmaf(qa.z, k2v, fmaf(qa.w, k3v, sc0))));
        sc1 = fmaf(qb.x, k0v, fmaf(qb.y, k1v, fmaf(qb.z, k2v, fmaf(qb.w, k3v, sc1))));
      }
      if (sp > tq0) sc0 = -1e30f;
      if (sp > tq1) sc1 = -1e30f;
      float mt0 = sc0, mt1 = sc1;
      #pragma unroll
      for (int off = 32; off; off >>= 1) {
        mt0 = fmaxf(mt0, __shfl_xor(mt0, off));
        mt1 = fmaxf(mt1, __shfl_xor(mt1, off));
      }
      float mn0 = fmaxf(mrow[ii], mt0), mn1 = fmaxf(mrow[ii + 1], mt1);
      float scl0 = __expf(mrow[ii] - mn0), scl1 = __expf(mrow[ii + 1] - mn1);
      float p0 = __expf(sc0 - mn0), p1 = __expf(sc1 - mn1);
      float s0sum = p0, s1sum = p1;
      #pragma unroll
      for (int off = 32; off; off >>= 1) { s0sum += __shfl_xor(s0sum, off); s1sum += __shfl_xor(s1sum, off); }
      lrow[ii] = lrow[ii] * scl0 + s0sum;  mrow[ii] = mn0;
      lrow[ii + 1] = lrow[ii + 1] * scl1 + s1sum; mrow[ii + 1] = mn1;
      float a0 = acc[ii] * scl0, a1 = acc[ii + 1] * scl1;
      #pragma unroll
      for (int s = 0; s < 64; ++s) {
        float vsl = Vst[lane][s];
        float ps0 = __builtin_bit_cast(float, __builtin_amdgcn_readlane(__builtin_bit_cast(int, p0), s));
        float ps1 = __builtin_bit_cast(float, __builtin_amdgcn_readlane(__builtin_bit_cast(int, p1), s));
        a0 = fmaf(ps0, vsl, a0);
        a1 = fmaf(ps1, vsl, a1);
      }
      acc[ii] = a0; acc[ii + 1] = a1;
    }
  }
  #pragma unroll
  for (int i = 0; i < 8; ++i) {
    int t = t0 + r0 + i;
    float o = acc[i] / lrow[i];
    ybf[(((size_t)((b << 10) | t)) << 10) + (hh << 6) + lane] = f2bf(o);
  }
}

// ---------- cmix token-shift mix -> xk, xr (bf16) ----------
__global__ __launch_bounds__(256) void mixk(const float* __restrict__ xn3,
    const float* __restrict__ tmk, const float* __restrict__ tmr,
    unsigned short* __restrict__ xkbf, unsigned short* __restrict__ xrbf) {
  int idx4 = blockIdx.x * 256 + threadIdx.x;   // 4096*1024/4
  int row = idx4 >> 8;
  int col = (idx4 & 255) << 2;
  int t = row & 1023;
  size_t off = ((size_t)idx4) << 2;
  float4 cur = *(const float4*)(xn3 + off);
  float4 prev = make_float4(0.f, 0.f, 0.f, 0.f);
  if (t > 0) prev = *(const float4*)(xn3 + off - 1024);
  float4 tk = *(const float4*)(tmk + col);
  float4 tr = *(const float4*)(tmr + col);
  float dx = prev.x - cur.x, dy = prev.y - cur.y, dz = prev.z - cur.z, dw = prev.w - cur.w;
  *(ushort4*)(xkbf + off) = make_ushort4(
      f2bf(cur.x + dx * tk.x), f2bf(cur.y + dy * tk.y), f2bf(cur.z + dz * tk.z), f2bf(cur.w + dw * tk.w));
  *(ushort4*)(xrbf + off) = make_ushort4(
      f2bf(cur.x + dx * tr.x), f2bf(cur.y + dy * tr.y), f2bf(cur.z + dz * tr.z), f2bf(cur.w + dw * tr.w));
}

// ---------- final: out = x2 + sigmoid(rraw) * vout ----------
__global__ __launch_bounds__(256) void finalk(const float* __restrict__ x2,
    const float* __restrict__ rraw, const float* __restrict__ vout,
    float* __restrict__ out) {
  int idx4 = blockIdx.x * 256 + threadIdx.x;   // 4096*1024/4
  size_t off = ((size_t)idx4) << 2;
  float4 xv = *(const float4*)(x2 + off);
  float4 rv = *(const float4*)(rraw + off);
  float4 vv = *(const float4*)(vout + off);
  float4 o;
  o.x = xv.x + vv.x / (1.f + __expf(-rv.x));
  o.y = xv.y + vv.y / (1.f + __expf(-rv.y));
  o.z = xv.z + vv.z / (1.f + __expf(-rv.z));
  o.w = xv.w + vv.w / (1.f + __expf(-rv.w));
  *(float4*)(out + off) = o;
}

// ---------- host launcher ----------
extern "C" void kernel_launch(void* const* d_in, const int* in_sizes, int n_in,
                              void* d_out, int out_size, void* d_ws, size_t ws_size,
                              hipStream_t stream) {
  (void)in_sizes; (void)n_in; (void)out_size;
  const float* x        = (const float*)d_in[0];
  const float* in_proj  = (const float*)d_in[1];
  const float* conv_w   = (const float*)d_in[2];
  const float* conv_b   = (const float*)d_in[3];
  const float* dt_bias  = (const float*)d_in[4];
  const float* A_log    = (const float*)d_in[5];
  const float* Dvec     = (const float*)d_in[6];
  const float* mnorm_w  = (const float*)d_in[7];
  const float* out_proj = (const float*)d_in[8];
  const float* attn_w   = (const float*)d_in[9];
  const float* proj_w   = (const float*)d_in[10];
  const float* tmk      = (const float*)d_in[11];
  const float* tmr      = (const float*)d_in[12];
  const float* key_w    = (const float*)d_in[13];
  const float* recept_w = (const float*)d_in[14];
  const float* value_w  = (const float*)d_in[15];
  float* out = (float*)d_out;

  if (ws_size < 199229440ull) return;   // workspace layout requires ~190 MiB

  char* ws = (char*)d_ws;
  unsigned short* Wt   = (unsigned short*)(ws + 0);
  unsigned short* Abf  = (unsigned short*)(ws + 8912896ull);    // 32 MiB: xn1/g/xn2/atty/kact
  unsigned short* Abf2 = (unsigned short*)(ws + 42467328ull);   // 16 MiB: z | xk,xr
  float* bigF = (float*)(ws + 59244544ull);                     // zxbcdt rest [4096][2208]
  float* big1 = (float*)(ws + 95420416ull);                     // xbc / mo / qkv / rraw
  float* big2 = (float*)(ws + 131072000ull);                    // ydin / po / vout
  float* x1   = (float*)(ws + 164626432ull);
  float* xn3  = (float*)(ws + 181403648ull);
  float* dtb  = (float*)(ws + 198180864ull);
  float* dab  = (float*)(ws + 198705152ull);
  unsigned short* zbf  = Abf2;
  unsigned short* xkbf = Abf2;
  unsigned short* xrbf = Abf2 + 4194304;   // 4096*1024

  dim3 b256(256);
  dim3 tb(32, 8);

  // ===== Phase A: mamba2 =====
  resrms_k<0, 0, 0><<<4096, b256, 0, stream>>>(x, nullptr, nullptr, Abf, nullptr);
  transp_k<<<dim3(64, 32), tb, 0, stream>>>(in_proj, Wt, 1024, 2048, 2048, 0, 4256);
  gemm_k<1><<<dim3(16, 32), b256, 0, stream>>>(Abf, Wt, zbf, 4096, 2048, 1024);          // z (bf16)
  transp_k<<<dim3(72, 32), tb, 0, stream>>>(in_proj, Wt, 1024, 2208, 2304, 2048, 4256);
  gemm_k<0><<<dim3(18, 32), b256, 0, stream>>>(Abf, Wt, bigF, 4096, 2208, 1024);         // xBC+dt (f32)
  dtk<<<512, b256, 0, stream>>>(bigF, dt_bias, A_log, dtb, dab);
  convk<<<34816, b256, 0, stream>>>(bigF, conv_w, conv_b, big1);                         // xbc_act
  scank<<<256, b256, 0, stream>>>(big1, dtb, dab, Dvec, big2);                           // ydin
  gnormk<<<4096, b256, 0, stream>>>(big2, zbf, mnorm_w, Abf);                            // g (bf16)
  transp_k<<<dim3(32, 64), tb, 0, stream>>>(out_proj, Wt, 2048, 1024, 1024, 0, 1024);
  gemm_k<0><<<dim3(8, 32), b256, 0, stream>>>(Abf, Wt, big1, 4096, 1024, 2048);          // mo
  resrms_k<1, 1, 0><<<4096, b256, 0, stream>>>(x, big1, x1, Abf, nullptr);               // x1, xn2

  // ===== Phase B: mqa =====
  transp_k<<<dim3(36, 32), tb, 0, stream>>>(attn_w, Wt, 1024, 1152, 1152, 0, 1152);
  gemm_k<0><<<dim3(9, 32), b256, 0, stream>>>(Abf, Wt, big1, 4096, 1152, 1024);          // qkv
  attnk<<<dim3(32, 16, 4), b256, 0, stream>>>(big1, Abf);                                // atty (bf16)
  transp_k<<<dim3(32, 32), tb, 0, stream>>>(proj_w, Wt, 1024, 1024, 1024, 0, 1024);
  gemm_k<0><<<dim3(8, 32), b256, 0, stream>>>(Abf, Wt, big2, 4096, 1024, 1024);          // po
  resrms_k<1, 1, 1><<<4096, b256, 0, stream>>>(x1, big2, x1, Abf, xn3);                  // x2 (in x1), xn3

  // ===== Phase C: cmix =====
  mixk<<<4096, b256, 0, stream>>>(xn3, tmk, tmr, xkbf, xrbf);
  transp_k<<<dim3(128, 32), tb, 0, stream>>>(key_w, Wt, 1024, 4096, 4096, 0, 4096);
  gemm_k<2><<<dim3(32, 32), b256, 0, stream>>>(xkbf, Wt, Abf, 4096, 4096, 1024);         // kact (bf16)
  transp_k<<<dim3(32, 128), tb, 0, stream>>>(value_w, Wt, 4096, 1024, 1024, 0, 1024);
  gemm_k<0><<<dim3(8, 32), b256, 0, stream>>>(Abf, Wt, big2, 4096, 1024, 4096);          // vout
  transp_k<<<dim3(32, 32), tb, 0, stream>>>(recept_w, Wt, 1024, 1024, 1024, 0, 1024);
  gemm_k<0><<<dim3(8, 32), b256, 0, stream>>>(xrbf, Wt, big1, 4096, 1024, 1024);         // rraw
  finalk<<<4096, b256, 0, stream>>>(x1, big1, big2, out);
}

// Round 2
// 949.433 us; speedup vs baseline: 1.4969x; 1.4969x over previous
//
#include <hip/hip_runtime.h>

// ---------- helpers ----------
__device__ __forceinline__ unsigned short f2bf(float f) {
  unsigned u = __builtin_bit_cast(unsigned, f);
  u = u + 0x7fffu + ((u >> 16) & 1u);      // RNE
  return (unsigned short)(u >> 16);
}
__device__ __forceinline__ float bf2f(unsigned short u) {
  return __builtin_bit_cast(float, ((unsigned)u) << 16);
}

typedef __bf16 bf16x8 __attribute__((ext_vector_type(8)));
typedef float  f32x4  __attribute__((ext_vector_type(4)));

#define GLD16(gp, lp) __builtin_amdgcn_global_load_lds( \
    (const __attribute__((address_space(1))) unsigned int*)(gp), \
    (__attribute__((address_space(3))) unsigned int*)(lp), 16, 0, 0)

// ---------- rmsnorm (+ optional residual) ----------
template<int HAS_DELTA, int WRITE_SUM, int WRITE_N32>
__global__ __launch_bounds__(256) void resrms_k(const float* __restrict__ xin,
    const float* __restrict__ delta, float* __restrict__ xsum,
    unsigned short* __restrict__ nbf, float* __restrict__ nf32) {
  int row = blockIdx.x, tid = threadIdx.x;
  size_t base = ((size_t)row << 10) + ((size_t)tid << 2);
  float4 v = *(const float4*)(xin + base);
  if (HAS_DELTA) {
    float4 d = *(const float4*)(delta + base);
    v.x += d.x; v.y += d.y; v.z += d.z; v.w += d.w;
  }
  if (WRITE_SUM) *(float4*)(xsum + base) = v;
  float ss = v.x*v.x + v.y*v.y + v.z*v.z + v.w*v.w;
  #pragma unroll
  for (int off = 32; off; off >>= 1) ss += __shfl_xor(ss, off);
  __shared__ float ws4[4];
  if ((tid & 63) == 0) ws4[tid >> 6] = ss;
  __syncthreads();
  float tot = ws4[0] + ws4[1] + ws4[2] + ws4[3];
  float sc = rsqrtf(tot * (1.0f / 1024.0f) + 1e-5f);
  *(ushort4*)(nbf + base) = make_ushort4(f2bf(v.x*sc), f2bf(v.y*sc), f2bf(v.z*sc), f2bf(v.w*sc));
  if (WRITE_N32) {
    float4 n; n.x = v.x*sc; n.y = v.y*sc; n.z = v.z*sc; n.w = v.w*sc;
    *(float4*)(nf32 + base) = n;
  }
}

// ---------- transpose+convert: W[K][ldw] f32 -> Wt[Npad][K] bf16 ----------
__global__ void transp_k(const float* __restrict__ W, unsigned short* __restrict__ Wt,
                         int K, int Ncols, int Npad, int col_off, int ldw) {
  __shared__ float t[32][33];
  int n0 = blockIdx.x << 5, k0 = blockIdx.y << 5;
  int tx = threadIdx.x, ty = threadIdx.y;
  #pragma unroll
  for (int rr = 0; rr < 32; rr += 8) {
    int k = k0 + rr + ty, n = n0 + tx;
    t[rr + ty][tx] = (n < Ncols) ? W[(size_t)k * ldw + col_off + n] : 0.f;
  }
  __syncthreads();
  #pragma unroll
  for (int rr = 0; rr < 32; rr += 8) {
    int nrow = n0 + rr + ty;
    Wt[(size_t)nrow * K + k0 + tx] = f2bf(t[tx][rr + ty]);
  }
}

// ---------- bf16 MFMA GEMM (m97 structure): C[M][N] = A[M][K] * Bt[N][K]^T ----------
// EPI: 0 = f32 store, 1 = bf16 store, 2 = erf-activation -> bf16 store
template<int EPI>
__global__ __launch_bounds__(256) void gemm_k(const unsigned short* __restrict__ A,
    const unsigned short* __restrict__ Bt, void* __restrict__ Cout,
    int M, int N, int K) {
  __shared__ unsigned short As[128 * 32];
  __shared__ unsigned short Bs[128 * 32];
  int tid = threadIdx.x;
  int wave = tid >> 6, lane = tid & 63;
  int m0 = blockIdx.y << 7, n0 = blockIdx.x << 7;
  int wm = (wave >> 1) << 6, wn = (wave & 1) << 6;
  int fr = lane & 15, g = lane >> 4;
  f32x4 acc[4][4];
  #pragma unroll
  for (int i = 0; i < 4; ++i)
    #pragma unroll
    for (int j = 0; j < 4; ++j) acc[i][j] = (f32x4){0.f, 0.f, 0.f, 0.f};
  // staging: wave stages rows [wave*32, wave*32+32) of A and B, 2 x 1KB instrs each
  const int srow = (wave << 5) + (lane >> 2);     // + q*16
  const int skp = (lane & 3) << 3;
  const unsigned short* Asrc = A + (size_t)(m0 + srow) * K + skp;
  const unsigned short* Bsrc = Bt + (size_t)(n0 + srow) * K + skp;
  unsigned short* Ad0 = &As[(wave << 5) << 5];
  unsigned short* Ad1 = &As[((wave << 5) + 16) << 5];
  unsigned short* Bd0 = &Bs[(wave << 5) << 5];
  unsigned short* Bd1 = &Bs[((wave << 5) + 16) << 5];
  const size_t rowskip = (size_t)16 * K;
  for (int k0 = 0; k0 < K; k0 += 32) {
    __syncthreads();
    GLD16(Asrc + k0, Ad0);
    GLD16(Asrc + k0 + rowskip, Ad1);
    GLD16(Bsrc + k0, Bd0);
    GLD16(Bsrc + k0 + rowskip, Bd1);
    __syncthreads();
    bf16x8 af[4], bv[4];
    #pragma unroll
    for (int i = 0; i < 4; ++i) af[i] = *(const bf16x8*)&As[((wm + (i << 4) + fr) << 5) + (g << 3)];
    #pragma unroll
    for (int j = 0; j < 4; ++j) bv[j] = *(const bf16x8*)&Bs[((wn + (j << 4) + fr) << 5) + (g << 3)];
    #pragma unroll
    for (int i = 0; i < 4; ++i)
      #pragma unroll
      for (int j = 0; j < 4; ++j)
        acc[i][j] = __builtin_amdgcn_mfma_f32_16x16x32_bf16(af[i], bv[j], acc[i][j], 0, 0, 0);
  }
  int rin = g << 2;
  #pragma unroll
  for (int i = 0; i < 4; ++i) {
    #pragma unroll
    for (int j = 0; j < 4; ++j) {
      int col = n0 + wn + (j << 4) + fr;
      if (col < N) {
        #pragma unroll
        for (int rr = 0; rr < 4; ++rr) {
          int row = m0 + wm + (i << 4) + rin + rr;
          float v = acc[i][j][rr];
          if (EPI == 0) {
            ((float*)Cout)[(size_t)row * N + col] = v;
          } else if (EPI == 1) {
            ((unsigned short*)Cout)[(size_t)row * N + col] = f2bf(v);
          } else {
            float kv = 0.5f * (1.0f + erff((v - 0.70710678f) * 2.5066283f));
            ((unsigned short*)Cout)[(size_t)row * N + col] = f2bf(kv);
          }
        }
      }
    }
  }
}

// ---------- dt / dA ----------
__global__ __launch_bounds__(256) void dtk(const float* __restrict__ zxr,
    const float* __restrict__ dt_bias, const float* __restrict__ A_log,
    float* __restrict__ dt, float* __restrict__ dA) {
  int i = blockIdx.x * 256 + threadIdx.x;     // 4096*32
  int r = i >> 5, hh = i & 31;
  float v = zxr[(size_t)r * 2208 + 2176 + hh] + dt_bias[hh];
  float dtv = (v > 20.f) ? v : log1pf(__expf(v));
  float Ah = -__expf(A_log[hh]);
  dt[i] = dtv;
  dA[i] = __expf(dtv * Ah);
}

// ---------- causal depthwise conv(4) + silu ----------
__global__ __launch_bounds__(256) void convk(const float* __restrict__ zxr,
    const float* __restrict__ conv_w, const float* __restrict__ conv_b,
    float* __restrict__ xbc) {
  int i = blockIdx.x * 256 + threadIdx.x;     // 4*1024*2176
  if (i >= 4 * 1024 * 2176) return;
  int c = i % 2176; int bt = i / 2176; int t = bt & 1023;
  const float* col = zxr + (size_t)bt * 2208 + c;
  float acc = conv_b[c];
  float w0 = conv_w[c * 4 + 0], w1 = conv_w[c * 4 + 1], w2 = conv_w[c * 4 + 2], w3 = conv_w[c * 4 + 3];
  if (t >= 3) acc = fmaf(col[-3 * 2208], w0, acc);
  if (t >= 2) acc = fmaf(col[-2 * 2208], w1, acc);
  if (t >= 1) acc = fmaf(col[-1 * 2208], w2, acc);
  acc = fmaf(col[0], w3, acc);
  xbc[(size_t)bt * 2176 + c] = acc / (1.f + __expf(-acc));
}

// ---------- sequential SSM scan ----------
__global__ __launch_bounds__(256) void scank(const float* __restrict__ xbc,
    const float* __restrict__ dtv, const float* __restrict__ dav,
    const float* __restrict__ Dv, float* __restrict__ ydin) {
  const int bid = blockIdx.x;                 // 256 = b(4) * h(32) * ph(2)
  const int ph = bid & 1, h = (bid >> 1) & 31, b = bid >> 6;
  const int tid = threadIdx.x;
  const int p = (ph << 5) + (tid >> 3), n0 = (tid & 7) << 3;
  float hr[8] = {0, 0, 0, 0, 0, 0, 0, 0};
  const float Dh = Dv[h];
  const float* xb = xbc + ((size_t)(b << 10)) * 2176;
  const float* dtb = dtv + (((size_t)(b << 10)) << 5) + h;
  const float* dab = dav + (((size_t)(b << 10)) << 5) + h;
  float* yb = ydin + (((size_t)(b << 10)) << 11) + (h << 6) + p;
  const int xoff = (h << 6) + p;

#define DECLP(s) float x##s, dq##s, da##s; float4 B0##s, B1##s, C0##s, C1##s;
#define LOADP(s, tt) { const float* row_ = xb + (size_t)(tt) * 2176; \
    x##s = row_[xoff]; dq##s = dtb[(tt) << 5]; da##s = dab[(tt) << 5]; \
    B0##s = *(const float4*)(row_ + 2048 + n0); B1##s = *(const float4*)(row_ + 2052 + n0); \
    C0##s = *(const float4*)(row_ + 2112 + n0); C1##s = *(const float4*)(row_ + 2116 + n0); }
#define STEPP(s, tt) { float cm_ = dq##s * x##s; float pt_; \
    hr[0] = fmaf(da##s, hr[0], cm_ * B0##s.x); pt_  = hr[0] * C0##s.x; \
    hr[1] = fmaf(da##s, hr[1], cm_ * B0##s.y); pt_ += hr[1] * C0##s.y; \
    hr[2] = fmaf(da##s, hr[2], cm_ * B0##s.z); pt_ += hr[2] * C0##s.z; \
    hr[3] = fmaf(da##s, hr[3], cm_ * B0##s.w); pt_ += hr[3] * C0##s.w; \
    hr[4] = fmaf(da##s, hr[4], cm_ * B1##s.x); pt_ += hr[4] * C1##s.x; \
    hr[5] = fmaf(da##s, hr[5], cm_ * B1##s.y); pt_ += hr[5] * C1##s.y; \
    hr[6] = fmaf(da##s, hr[6], cm_ * B1##s.z); pt_ += hr[6] * C1##s.z; \
    hr[7] = fmaf(da##s, hr[7], cm_ * B1##s.w); pt_ += hr[7] * C1##s.w; \
    pt_ += __shfl_xor(pt_, 1); pt_ += __shfl_xor(pt_, 2); pt_ += __shfl_xor(pt_, 4); \
    if ((tid & 7) == 0) yb[(size_t)(tt) << 11] = fmaf(Dh, x##s, pt_); }

  DECLP(0) DECLP(1) DECLP(2) DECLP(3)
  LOADP(0, 0) LOADP(1, 1) LOADP(2, 2) LOADP(3, 3)
  int t = 0;
  for (; t < 1020; t += 4) {
    STEPP(0, t)     LOADP(0, t + 4)
    STEPP(1, t + 1) LOADP(1, t + 5)
    STEPP(2, t + 2) LOADP(2, t + 6)
    STEPP(3, t + 3) LOADP(3, t + 7)
  }
  STEPP(0, 1020) STEPP(1, 1021) STEPP(2, 1022) STEPP(3, 1023)
#undef DECLP
#undef LOADP
#undef STEPP
}

// ---------- g = ydin * silu(z); rmsnorm(2048) * mnorm_w -> bf16 ----------
__global__ __launch_bounds__(256) void gnormk(const float* __restrict__ ydin,
    const unsigned short* __restrict__ zbf, const float* __restrict__ mw,
    unsigned short* __restrict__ gbf) {
  int row = blockIdx.x, tid = threadIdx.x;
  size_t base = ((size_t)row << 11) + ((size_t)tid << 3);
  float4 y0 = *(const float4*)(ydin + base);
  float4 y1 = *(const float4*)(ydin + base + 4);
  ushort4 z0 = *(const ushort4*)(zbf + base);
  ushort4 z1 = *(const ushort4*)(zbf + base + 4);
  float g[8];
  {
    float z;
    z = bf2f(z0.x); g[0] = y0.x * (z / (1.f + __expf(-z)));
    z = bf2f(z0.y); g[1] = y0.y * (z / (1.f + __expf(-z)));
    z = bf2f(z0.z); g[2] = y0.z * (z / (1.f + __expf(-z)));
    z = bf2f(z0.w); g[3] = y0.w * (z / (1.f + __expf(-z)));
    z = bf2f(z1.x); g[4] = y1.x * (z / (1.f + __expf(-z)));
    z = bf2f(z1.y); g[5] = y1.y * (z / (1.f + __expf(-z)));
    z = bf2f(z1.z); g[6] = y1.z * (z / (1.f + __expf(-z)));
    z = bf2f(z1.w); g[7] = y1.w * (z / (1.f + __expf(-z)));
  }
  float ss = 0.f;
  #pragma unroll
  for (int k = 0; k < 8; ++k) ss += g[k] * g[k];
  #pragma unroll
  for (int off = 32; off; off >>= 1) ss += __shfl_xor(ss, off);
  __shared__ float ws4[4];
  if ((tid & 63) == 0) ws4[tid >> 6] = ss;
  __syncthreads();
  float tot = ws4[0] + ws4[1] + ws4[2] + ws4[3];
  float sc = rsqrtf(tot * (1.f / 2048.f) + 1e-5f);
  int c0 = tid << 3;
  float4 m0 = *(const float4*)(mw + c0);
  float4 m1 = *(const float4*)(mw + c0 + 4);
  *(ushort4*)(gbf + base)     = make_ushort4(f2bf(g[0]*sc*m0.x), f2bf(g[1]*sc*m0.y), f2bf(g[2]*sc*m0.z), f2bf(g[3]*sc*m0.w));
  *(ushort4*)(gbf + base + 4) = make_ushort4(f2bf(g[4]*sc*m1.x), f2bf(g[5]*sc*m1.y), f2bf(g[6]*sc*m1.z), f2bf(g[7]*sc*m1.w));
}

// ---------- MQA causal attention (MFMA flash), out bf16 ----------
// grid: 1024 blocks; id: b = id&3, h = (id>>2)&15, qt = id>>6 (load-balances qt across CUs)
__global__ __launch_bounds__(256) void attnk(const float* __restrict__ qkv,
                                             unsigned short* __restrict__ ybf) {
  __shared__ unsigned short Qs[64][72];
  __shared__ unsigned short Ks[64][72];
  __shared__ unsigned short VT[64][72];   // VT[d][key]
  __shared__ unsigned short Ps[4][16][72];
  const int id = blockIdx.x;
  const int b = id & 3, h = (id >> 2) & 15, qt = id >> 6;
  const int t0 = qt << 6;
  const int tid = threadIdx.x, w = tid >> 6, lane = tid & 63;
  const int fr = lane & 15, g = lane >> 4;

  // stage Q (scaled by 1/sqrt(64))
  {
    int r = tid >> 2, d0 = (tid & 3) << 4;
    const float* src = qkv + ((size_t)((b << 10) | (t0 + r))) * 1152 + (h << 6) + d0;
    #pragma unroll
    for (int i = 0; i < 4; ++i) {
      float4 v = *(const float4*)(src + 4 * i);
      *(ushort4*)&Qs[r][d0 + 4 * i] =
          make_ushort4(f2bf(v.x * 0.125f), f2bf(v.y * 0.125f), f2bf(v.z * 0.125f), f2bf(v.w * 0.125f));
    }
  }
  __syncthreads();
  bf16x8 afQ0 = *(const bf16x8*)&Qs[(w << 4) + fr][g << 3];
  bf16x8 afQ1 = *(const bf16x8*)&Qs[(w << 4) + fr][32 + (g << 3)];

  f32x4 acc_o[4];
  #pragma unroll
  for (int i = 0; i < 4; ++i) acc_o[i] = (f32x4){0.f, 0.f, 0.f, 0.f};
  float m[4] = {-1e30f, -1e30f, -1e30f, -1e30f};
  float l[4] = {0.f, 0.f, 0.f, 0.f};
  const int qrow = t0 + (w << 4) + (g << 2);   // + r

  for (int kt = 0; kt <= qt; ++kt) {
    const int s0 = kt << 6;
    __syncthreads();
    // stage K
    {
      int r = tid >> 2, d0 = (tid & 3) << 4;
      const float* src = qkv + ((size_t)((b << 10) | (s0 + r))) * 1152 + 1024 + d0;
      #pragma unroll
      for (int i = 0; i < 4; ++i) {
        float4 v = *(const float4*)(src + 4 * i);
        *(ushort4*)&Ks[r][d0 + 4 * i] = make_ushort4(f2bf(v.x), f2bf(v.y), f2bf(v.z), f2bf(v.w));
      }
    }
    // stage V transposed
    {
      int r0 = (tid & 15) << 2, d0 = (tid >> 4) << 2;
      const float* src = qkv + ((size_t)((b << 10) | (s0 + r0))) * 1152 + 1088 + d0;
      float4 v0 = *(const float4*)(src);
      float4 v1 = *(const float4*)(src + 1152);
      float4 v2 = *(const float4*)(src + 2304);
      float4 v3 = *(const float4*)(src + 3456);
      *(ushort4*)&VT[d0 + 0][r0] = make_ushort4(f2bf(v0.x), f2bf(v1.x), f2bf(v2.x), f2bf(v3.x));
      *(ushort4*)&VT[d0 + 1][r0] = make_ushort4(f2bf(v0.y), f2bf(v1.y), f2bf(v2.y), f2bf(v3.y));
      *(ushort4*)&VT[d0 + 2][r0] = make_ushort4(f2bf(v0.z), f2bf(v1.z), f2bf(v2.z), f2bf(v3.z));
      *(ushort4*)&VT[d0 + 3][r0] = make_ushort4(f2bf(v0.w), f2bf(v1.w), f2bf(v2.w), f2bf(v3.w));
    }
    __syncthreads();
    // QK^T: S[16 q][64 key] per wave
    f32x4 s4[4];
    #pragma unroll
    for (int jt = 0; jt < 4; ++jt) {
      bf16x8 b0 = *(const bf16x8*)&Ks[(jt << 4) + fr][g << 3];
      bf16x8 b1 = *(const bf16x8*)&Ks[(jt << 4) + fr][32 + (g << 3)];
      f32x4 z4 = (f32x4){0.f, 0.f, 0.f, 0.f};
      z4 = __builtin_amdgcn_mfma_f32_16x16x32_bf16(afQ0, b0, z4, 0, 0, 0);
      z4 = __builtin_amdgcn_mfma_f32_16x16x32_bf16(afQ1, b1, z4, 0, 0, 0);
      s4[jt] = z4;
    }
    if (kt == qt) {   // causal mask on diagonal tile only
      #pragma unroll
      for (int jt = 0; jt < 4; ++jt) {
        int key = s0 + (jt << 4) + fr;
        #pragma unroll
        for (int r = 0; r < 4; ++r)
          if (key > qrow + r) s4[jt][r] = -1e30f;
      }
    }
    // online softmax (per reg-row r; 16-lane fr-group shares a row)
    #pragma unroll
    for (int r = 0; r < 4; ++r) {
      float mt = fmaxf(fmaxf(s4[0][r], s4[1][r]), fmaxf(s4[2][r], s4[3][r]));
      #pragma unroll
      for (int off = 8; off; off >>= 1) mt = fmaxf(mt, __shfl_xor(mt, off));
      float mn = fmaxf(m[r], mt);
      float scl = __expf(m[r] - mn);
      m[r] = mn;
      float ps = 0.f;
      #pragma unroll
      for (int jt = 0; jt < 4; ++jt) {
        float p = __expf(s4[jt][r] - mn);
        ps += p;
        Ps[w][(g << 2) + r][(jt << 4) + fr] = f2bf(p);
      }
      #pragma unroll
      for (int off = 8; off; off >>= 1) ps += __shfl_xor(ps, off);
      l[r] = l[r] * scl + ps;
      acc_o[0][r] *= scl; acc_o[1][r] *= scl; acc_o[2][r] *= scl; acc_o[3][r] *= scl;
    }
    // PV: O[16 q][64 d] += P[16][64] * V[64][64]
    #pragma unroll
    for (int ks = 0; ks < 2; ++ks) {
      bf16x8 ap = *(const bf16x8*)&Ps[w][fr][(ks << 5) + (g << 3)];
      #pragma unroll
      for (int dt = 0; dt < 4; ++dt) {
        bf16x8 bv = *(const bf16x8*)&VT[(dt << 4) + fr][(ks << 5) + (g << 3)];
        acc_o[dt] = __builtin_amdgcn_mfma_f32_16x16x32_bf16(ap, bv, acc_o[dt], 0, 0, 0);
      }
    }
  }
  // epilogue: O /= l
  #pragma unroll
  for (int dt = 0; dt < 4; ++dt) {
    #pragma unroll
    for (int r = 0; r < 4; ++r) {
      float o = acc_o[dt][r] / l[r];
      int t = t0 + (w << 4) + (g << 2) + r;
      ybf[(((size_t)((b << 10) | t)) << 10) + (h << 6) + (dt << 4) + fr] = f2bf(o);
    }
  }
}

// ---------- cmix token-shift mix -> xk, xr (bf16) ----------
__global__ __launch_bounds__(256) void mixk(const float* __restrict__ xn3,
    const float* __restrict__ tmk, const float* __restrict__ tmr,
    unsigned short* __restrict__ xkbf, unsigned short* __restrict__ xrbf) {
  int idx4 = blockIdx.x * 256 + threadIdx.x;   // 4096*1024/4
  int col = (idx4 & 255) << 2;
  int row = idx4 >> 8;
  int t = row & 1023;
  size_t off = ((size_t)idx4) << 2;
  float4 cur = *(const float4*)(xn3 + off);
  float4 prev = make_float4(0.f, 0.f, 0.f, 0.f);
  if (t > 0) prev = *(const float4*)(xn3 + off - 1024);
  float4 tk = *(const float4*)(tmk + col);
  float4 tr = *(const float4*)(tmr + col);
  float dx = prev.x - cur.x, dy = prev.y - cur.y, dz = prev.z - cur.z, dw = prev.w - cur.w;
  *(ushort4*)(xkbf + off) = make_ushort4(
      f2bf(cur.x + dx * tk.x), f2bf(cur.y + dy * tk.y), f2bf(cur.z + dz * tk.z), f2bf(cur.w + dw * tk.w));
  *(ushort4*)(xrbf + off) = make_ushort4(
      f2bf(cur.x + dx * tr.x), f2bf(cur.y + dy * tr.y), f2bf(cur.z + dz * tr.z), f2bf(cur.w + dw * tr.w));
}

// ---------- final: out = x2 + sigmoid(rraw) * vout ----------
__global__ __launch_bounds__(256) void finalk(const float* __restrict__ x2,
    const float* __restrict__ rraw, const float* __restrict__ vout,
    float* __restrict__ out) {
  int idx4 = blockIdx.x * 256 + threadIdx.x;   // 4096*1024/4
  size_t off = ((size_t)idx4) << 2;
  float4 xv = *(const float4*)(x2 + off);
  float4 rv = *(const float4*)(rraw + off);
  float4 vv = *(const float4*)(vout + off);
  float4 o;
  o.x = xv.x + vv.x / (1.f + __expf(-rv.x));
  o.y = xv.y + vv.y / (1.f + __expf(-rv.y));
  o.z = xv.z + vv.z / (1.f + __expf(-rv.z));
  o.w = xv.w + vv.w / (1.f + __expf(-rv.w));
  *(float4*)(out + off) = o;
}

// ---------- host launcher ----------
extern "C" void kernel_launch(void* const* d_in, const int* in_sizes, int n_in,
                              void* d_out, int out_size, void* d_ws, size_t ws_size,
                              hipStream_t stream) {
  (void)in_sizes; (void)n_in; (void)out_size;
  const float* x        = (const float*)d_in[0];
  const float* in_proj  = (const float*)d_in[1];
  const float* conv_w   = (const float*)d_in[2];
  const float* conv_b   = (const float*)d_in[3];
  const float* dt_bias  = (const float*)d_in[4];
  const float* A_log    = (const float*)d_in[5];
  const float* Dvec     = (const float*)d_in[6];
  const float* mnorm_w  = (const float*)d_in[7];
  const float* out_proj = (const float*)d_in[8];
  const float* attn_w   = (const float*)d_in[9];
  const float* proj_w   = (const float*)d_in[10];
  const float* tmk      = (const float*)d_in[11];
  const float* tmr      = (const float*)d_in[12];
  const float* key_w    = (const float*)d_in[13];
  const float* recept_w = (const float*)d_in[14];
  const float* value_w  = (const float*)d_in[15];
  float* out = (float*)d_out;

  if (ws_size < 199229440ull) return;   // workspace layout requires ~190 MiB

  char* ws = (char*)d_ws;
  unsigned short* Wt   = (unsigned short*)(ws + 0);
  unsigned short* Abf  = (unsigned short*)(ws + 8912896ull);    // xn1/g/xn2/atty/kact
  unsigned short* Abf2 = (unsigned short*)(ws + 42467328ull);   // z | xk,xr
  float* bigF = (float*)(ws + 59244544ull);                     // zxbcdt rest [4096][2208]
  float* big1 = (float*)(ws + 95420416ull);                     // xbc / mo / qkv / rraw
  float* big2 = (float*)(ws + 131072000ull);                    // ydin / po / vout
  float* x1   = (float*)(ws + 164626432ull);
  float* xn3  = (float*)(ws + 181403648ull);
  float* dtb  = (float*)(ws + 198180864ull);
  float* dab  = (float*)(ws + 198705152ull);
  unsigned short* zbf  = Abf2;
  unsigned short* xkbf = Abf2;
  unsigned short* xrbf = Abf2 + 4194304;   // 4096*1024

  dim3 b256(256);
  dim3 tb(32, 8);

  // ===== Phase A: mamba2 =====
  resrms_k<0, 0, 0><<<4096, b256, 0, stream>>>(x, nullptr, nullptr, Abf, nullptr);
  transp_k<<<dim3(64, 32), tb, 0, stream>>>(in_proj, Wt, 1024, 2048, 2048, 0, 4256);
  gemm_k<1><<<dim3(16, 32), b256, 0, stream>>>(Abf, Wt, zbf, 4096, 2048, 1024);          // z (bf16)
  transp_k<<<dim3(72, 32), tb, 0, stream>>>(in_proj, Wt, 1024, 2208, 2304, 2048, 4256);
  gemm_k<0><<<dim3(18, 32), b256, 0, stream>>>(Abf, Wt, bigF, 4096, 2208, 1024);         // xBC+dt (f32)
  dtk<<<512, b256, 0, stream>>>(bigF, dt_bias, A_log, dtb, dab);
  convk<<<34816, b256, 0, stream>>>(bigF, conv_w, conv_b, big1);                         // xbc_act
  scank<<<256, b256, 0, stream>>>(big1, dtb, dab, Dvec, big2);                           // ydin
  gnormk<<<4096, b256, 0, stream>>>(big2, zbf, mnorm_w, Abf);                            // g (bf16)
  transp_k<<<dim3(32, 64), tb, 0, stream>>>(out_proj, Wt, 2048, 1024, 1024, 0, 1024);
  gemm_k<0><<<dim3(8, 32), b256, 0, stream>>>(Abf, Wt, big1, 4096, 1024, 2048);          // mo
  resrms_k<1, 1, 0><<<4096, b256, 0, stream>>>(x, big1, x1, Abf, nullptr);               // x1, xn2

  // ===== Phase B: mqa =====
  transp_k<<<dim3(36, 32), tb, 0, stream>>>(attn_w, Wt, 1024, 1152, 1152, 0, 1152);
  gemm_k<0><<<dim3(9, 32), b256, 0, stream>>>(Abf, Wt, big1, 4096, 1152, 1024);          // qkv
  attnk<<<1024, b256, 0, stream>>>(big1, Abf);                                           // atty (bf16)
  transp_k<<<dim3(32, 32), tb, 0, stream>>>(proj_w, Wt, 1024, 1024, 1024, 0, 1024);
  gemm_k<0><<<dim3(8, 32), b256, 0, stream>>>(Abf, Wt, big2, 4096, 1024, 1024);          // po
  resrms_k<1, 1, 1><<<4096, b256, 0, stream>>>(x1, big2, x1, Abf, xn3);                  // x2 (in x1), xn3

  // ===== Phase C: cmix =====
  mixk<<<4096, b256, 0, stream>>>(xn3, tmk, tmr, xkbf, xrbf);
  transp_k<<<dim3(128, 32), tb, 0, stream>>>(key_w, Wt, 1024, 4096, 4096, 0, 4096);
  gemm_k<2><<<dim3(32, 32), b256, 0, stream>>>(xkbf, Wt, Abf, 4096, 4096, 1024);         // kact (bf16)
  transp_k<<<dim3(32, 128), tb, 0, stream>>>(value_w, Wt, 4096, 1024, 1024, 0, 1024);
  gemm_k<0><<<dim3(8, 32), b256, 0, stream>>>(Abf, Wt, big2, 4096, 1024, 4096);          // vout
  transp_k<<<dim3(32, 32), tb, 0, stream>>>(recept_w, Wt, 1024, 1024, 1024, 0, 1024);
  gemm_k<0><<<dim3(8, 32), b256, 0, stream>>>(xrbf, Wt, big1, 4096, 1024, 1024);         // rraw
  finalk<<<4096, b256, 0, stream>>>(x1, big1, big2, out);
}

// Round 3
// 632.717 us; speedup vs baseline: 2.2462x; 1.5006x over previous
//
#include <hip/hip_runtime.h>

// ---------- helpers ----------
__device__ __forceinline__ unsigned short f2bf(float f) {
  unsigned u = __builtin_bit_cast(unsigned, f);
  u = u + 0x7fffu + ((u >> 16) & 1u);      // RNE
  return (unsigned short)(u >> 16);
}
__device__ __forceinline__ float bf2f(unsigned short u) {
  return __builtin_bit_cast(float, ((unsigned)u) << 16);
}

typedef __bf16 bf16x8 __attribute__((ext_vector_type(8)));
typedef float  f32x4  __attribute__((ext_vector_type(4)));

#define GLD16(gp, lp) __builtin_amdgcn_global_load_lds( \
    (const __attribute__((address_space(1))) unsigned int*)(gp), \
    (__attribute__((address_space(3))) unsigned int*)(lp), 16, 0, 0)

// ---------- rmsnorm (+ optional residual) ----------
template<int HAS_DELTA, int WRITE_SUM, int WRITE_N32>
__global__ __launch_bounds__(256) void resrms_k(const float* __restrict__ xin,
    const float* __restrict__ delta, float* __restrict__ xsum,
    unsigned short* __restrict__ nbf, float* __restrict__ nf32) {
  int row = blockIdx.x, tid = threadIdx.x;
  size_t base = ((size_t)row << 10) + ((size_t)tid << 2);
  float4 v = *(const float4*)(xin + base);
  if (HAS_DELTA) {
    float4 d = *(const float4*)(delta + base);
    v.x += d.x; v.y += d.y; v.z += d.z; v.w += d.w;
  }
  if (WRITE_SUM) *(float4*)(xsum + base) = v;
  float ss = v.x*v.x + v.y*v.y + v.z*v.z + v.w*v.w;
  #pragma unroll
  for (int off = 32; off; off >>= 1) ss += __shfl_xor(ss, off);
  __shared__ float ws4[4];
  if ((tid & 63) == 0) ws4[tid >> 6] = ss;
  __syncthreads();
  float tot = ws4[0] + ws4[1] + ws4[2] + ws4[3];
  float sc = rsqrtf(tot * (1.0f / 1024.0f) + 1e-5f);
  *(ushort4*)(nbf + base) = make_ushort4(f2bf(v.x*sc), f2bf(v.y*sc), f2bf(v.z*sc), f2bf(v.w*sc));
  if (WRITE_N32) {
    float4 n; n.x = v.x*sc; n.y = v.y*sc; n.z = v.z*sc; n.w = v.w*sc;
    *(float4*)(nf32 + base) = n;
  }
}

// ---------- transpose+convert: W[K][ldw] f32 -> Wt[Npad][K] bf16 ----------
__global__ void transp_k(const float* __restrict__ W, unsigned short* __restrict__ Wt,
                         int K, int Ncols, int Npad, int col_off, int ldw) {
  __shared__ float t[32][33];
  int n0 = blockIdx.x << 5, k0 = blockIdx.y << 5;
  int tx = threadIdx.x, ty = threadIdx.y;
  #pragma unroll
  for (int rr = 0; rr < 32; rr += 8) {
    int k = k0 + rr + ty, n = n0 + tx;
    t[rr + ty][tx] = (n < Ncols) ? W[(size_t)k * ldw + col_off + n] : 0.f;
  }
  __syncthreads();
  #pragma unroll
  for (int rr = 0; rr < 32; rr += 8) {
    int nrow = n0 + rr + ty;
    Wt[(size_t)nrow * K + k0 + tx] = f2bf(t[tx][rr + ty]);
  }
}

// ---------- bf16 MFMA GEMM (m97 structure): C[M][N] = A[M][K] * Bt[N][K]^T ----------
template<int EPI>
__global__ __launch_bounds__(256) void gemm_k(const unsigned short* __restrict__ A,
    const unsigned short* __restrict__ Bt, void* __restrict__ Cout,
    int M, int N, int K) {
  __shared__ unsigned short As[128 * 32];
  __shared__ unsigned short Bs[128 * 32];
  int tid = threadIdx.x;
  int wave = tid >> 6, lane = tid & 63;
  int m0 = blockIdx.y << 7, n0 = blockIdx.x << 7;
  int wm = (wave >> 1) << 6, wn = (wave & 1) << 6;
  int fr = lane & 15, g = lane >> 4;
  f32x4 acc[4][4];
  #pragma unroll
  for (int i = 0; i < 4; ++i)
    #pragma unroll
    for (int j = 0; j < 4; ++j) acc[i][j] = (f32x4){0.f, 0.f, 0.f, 0.f};
  const int srow = (wave << 5) + (lane >> 2);
  const int skp = (lane & 3) << 3;
  const unsigned short* Asrc = A + (size_t)(m0 + srow) * K + skp;
  const unsigned short* Bsrc = Bt + (size_t)(n0 + srow) * K + skp;
  unsigned short* Ad0 = &As[(wave << 5) << 5];
  unsigned short* Ad1 = &As[((wave << 5) + 16) << 5];
  unsigned short* Bd0 = &Bs[(wave << 5) << 5];
  unsigned short* Bd1 = &Bs[((wave << 5) + 16) << 5];
  const size_t rowskip = (size_t)16 * K;
  for (int k0 = 0; k0 < K; k0 += 32) {
    __syncthreads();
    GLD16(Asrc + k0, Ad0);
    GLD16(Asrc + k0 + rowskip, Ad1);
    GLD16(Bsrc + k0, Bd0);
    GLD16(Bsrc + k0 + rowskip, Bd1);
    __syncthreads();
    bf16x8 af[4], bv[4];
    #pragma unroll
    for (int i = 0; i < 4; ++i) af[i] = *(const bf16x8*)&As[((wm + (i << 4) + fr) << 5) + (g << 3)];
    #pragma unroll
    for (int j = 0; j < 4; ++j) bv[j] = *(const bf16x8*)&Bs[((wn + (j << 4) + fr) << 5) + (g << 3)];
    #pragma unroll
    for (int i = 0; i < 4; ++i)
      #pragma unroll
      for (int j = 0; j < 4; ++j)
        acc[i][j] = __builtin_amdgcn_mfma_f32_16x16x32_bf16(af[i], bv[j], acc[i][j], 0, 0, 0);
  }
  int rin = g << 2;
  #pragma unroll
  for (int i = 0; i < 4; ++i) {
    #pragma unroll
    for (int j = 0; j < 4; ++j) {
      int col = n0 + wn + (j << 4) + fr;
      if (col < N) {
        #pragma unroll
        for (int rr = 0; rr < 4; ++rr) {
          int row = m0 + wm + (i << 4) + rin + rr;
          float v = acc[i][j][rr];
          if (EPI == 0) {
            ((float*)Cout)[(size_t)row * N + col] = v;
          } else if (EPI == 1) {
            ((unsigned short*)Cout)[(size_t)row * N + col] = f2bf(v);
          } else {
            float kv = 0.5f * (1.0f + erff((v - 0.70710678f) * 2.5066283f));
            ((unsigned short*)Cout)[(size_t)row * N + col] = f2bf(kv);
          }
        }
      }
    }
  }
}

// ---------- dt ----------
__global__ __launch_bounds__(256) void dtk(const float* __restrict__ zxr,
    const float* __restrict__ dt_bias, float* __restrict__ dt) {
  int i = blockIdx.x * 256 + threadIdx.x;     // 4096*32
  int r = i >> 5, hh = i & 31;
  float v = zxr[(size_t)r * 2208 + 2176 + hh] + dt_bias[hh];
  float dtv = (v > 20.f) ? v : log1pf(__expf(v));
  dt[i] = dtv;
}

// ---------- causal depthwise conv(4) + silu ----------
__global__ __launch_bounds__(256) void convk(const float* __restrict__ zxr,
    const float* __restrict__ conv_w, const float* __restrict__ conv_b,
    float* __restrict__ xbc) {
  int i = blockIdx.x * 256 + threadIdx.x;     // 4*1024*2176
  if (i >= 4 * 1024 * 2176) return;
  int c = i % 2176; int bt = i / 2176; int t = bt & 1023;
  const float* col = zxr + (size_t)bt * 2208 + c;
  float acc = conv_b[c];
  float w0 = conv_w[c * 4 + 0], w1 = conv_w[c * 4 + 1], w2 = conv_w[c * 4 + 2], w3 = conv_w[c * 4 + 3];
  if (t >= 3) acc = fmaf(col[-3 * 2208], w0, acc);
  if (t >= 2) acc = fmaf(col[-2 * 2208], w1, acc);
  if (t >= 1) acc = fmaf(col[-1 * 2208], w2, acc);
  acc = fmaf(col[0], w3, acc);
  xbc[(size_t)bt * 2176 + c] = acc / (1.f + __expf(-acc));
}

// ---------- SSD chunked scan, stage 1 ----------
// block id: h = id&31, b = (id>>5)&3, c = id>>7.  L=64 chunk.
// Computes Y_intra -> ydin, dh -> dhbuf, la -> labuf.
__global__ __launch_bounds__(256) void ssd1_k(const float* __restrict__ xbc,
    const float* __restrict__ dtb, const float* __restrict__ A_log,
    float* __restrict__ ydin, float* __restrict__ dhbuf, float* __restrict__ labuf) {
  __shared__ unsigned short Cs[64][68];   // [t][d]
  __shared__ unsigned short Bsm[64][68];  // [s][d]
  __shared__ unsigned short XT[64][68];   // [p][s]
  __shared__ unsigned short BT[64][68];   // [n][s] (scaled)
  __shared__ unsigned short Ms[64][68];   // [t][s]
  __shared__ float laS[64], dtS[64];
  const int id = blockIdx.x;
  const int h = id & 31, b = (id >> 5) & 3, c = id >> 7;
  const int tid = threadIdx.x, w = tid >> 6, lane = tid & 63;
  const int fr = lane & 15, g = lane >> 4;
  const size_t rowbase = (size_t)((b << 10) + (c << 6));

  // ---- stage C, B, X^T; wave0 computes la prefix ----
  {
    int r = tid >> 2, c0 = (tid & 3) << 4;
    const float* src = xbc + (rowbase + r) * 2176;
    #pragma unroll
    for (int i = 0; i < 4; ++i) {
      float4 v = *(const float4*)(src + 2112 + c0 + 4 * i);
      *(ushort4*)&Cs[r][c0 + 4 * i] = make_ushort4(f2bf(v.x), f2bf(v.y), f2bf(v.z), f2bf(v.w));
      float4 u = *(const float4*)(src + 2048 + c0 + 4 * i);
      *(ushort4*)&Bsm[r][c0 + 4 * i] = make_ushort4(f2bf(u.x), f2bf(u.y), f2bf(u.z), f2bf(u.w));
    }
  }
  {
    int r0 = (tid & 15) << 2, d0 = (tid >> 4) << 2;   // s-block, p-block
    const float* src = xbc + (rowbase + r0) * 2176 + (h << 6) + d0;
    float4 v0 = *(const float4*)(src);
    float4 v1 = *(const float4*)(src + 2176);
    float4 v2 = *(const float4*)(src + 4352);
    float4 v3 = *(const float4*)(src + 6528);
    *(ushort4*)&XT[d0 + 0][r0] = make_ushort4(f2bf(v0.x), f2bf(v1.x), f2bf(v2.x), f2bf(v3.x));
    *(ushort4*)&XT[d0 + 1][r0] = make_ushort4(f2bf(v0.y), f2bf(v1.y), f2bf(v2.y), f2bf(v3.y));
    *(ushort4*)&XT[d0 + 2][r0] = make_ushort4(f2bf(v0.z), f2bf(v1.z), f2bf(v2.z), f2bf(v3.z));
    *(ushort4*)&XT[d0 + 3][r0] = make_ushort4(f2bf(v0.w), f2bf(v1.w), f2bf(v2.w), f2bf(v3.w));
  }
  if (w == 0) {
    float Ah = -__expf(A_log[h]);
    float dtv = dtb[(rowbase + lane) * 32 + h];
    float v = dtv * Ah;
    #pragma unroll
    for (int off = 1; off < 64; off <<= 1) {
      float u = __shfl_up(v, off);
      if (lane >= off) v += u;
    }
    laS[lane] = v; dtS[lane] = dtv;
    labuf[(size_t)((((b << 4) | c) << 5 | h) << 6) + lane] = v;
  }
  __syncthreads();

  // ---- BT staging (scaled B^T) overlapped with G MFMA ----
  const int wr = w >> 1, wc = w & 1;
  f32x4 gf[2][2];
  #pragma unroll
  for (int i = 0; i < 2; ++i)
    #pragma unroll
    for (int j = 0; j < 2; ++j) gf[i][j] = (f32x4){0.f, 0.f, 0.f, 0.f};
  {
    int r0 = (tid & 15) << 2, d0 = (tid >> 4) << 2;   // s-block, n-block
    const float* src = xbc + (rowbase + r0) * 2176 + 2048 + d0;
    float la63 = laS[63];
    float4 v0 = *(const float4*)(src);
    float4 v1 = *(const float4*)(src + 2176);
    float4 v2 = *(const float4*)(src + 4352);
    float4 v3 = *(const float4*)(src + 6528);
    float w0 = __expf(la63 - laS[r0 + 0]) * dtS[r0 + 0];
    float w1 = __expf(la63 - laS[r0 + 1]) * dtS[r0 + 1];
    float w2 = __expf(la63 - laS[r0 + 2]) * dtS[r0 + 2];
    float w3 = __expf(la63 - laS[r0 + 3]) * dtS[r0 + 3];
    *(ushort4*)&BT[d0 + 0][r0] = make_ushort4(f2bf(v0.x*w0), f2bf(v1.x*w1), f2bf(v2.x*w2), f2bf(v3.x*w3));
    *(ushort4*)&BT[d0 + 1][r0] = make_ushort4(f2bf(v0.y*w0), f2bf(v1.y*w1), f2bf(v2.y*w2), f2bf(v3.y*w3));
    *(ushort4*)&BT[d0 + 2][r0] = make_ushort4(f2bf(v0.z*w0), f2bf(v1.z*w1), f2bf(v2.z*w2), f2bf(v3.z*w3));
    *(ushort4*)&BT[d0 + 3][r0] = make_ushort4(f2bf(v0.w*w0), f2bf(v1.w*w1), f2bf(v2.w*w2), f2bf(v3.w*w3));
  }
  #pragma unroll
  for (int ks = 0; ks < 2; ++ks) {
    bf16x8 ca[2], bb[2];
    #pragma unroll
    for (int i = 0; i < 2; ++i) ca[i] = *(const bf16x8*)&Cs[(wr << 5) + (i << 4) + fr][(ks << 5) + (g << 3)];
    #pragma unroll
    for (int j = 0; j < 2; ++j) bb[j] = *(const bf16x8*)&Bsm[(wc << 5) + (j << 4) + fr][(ks << 5) + (g << 3)];
    #pragma unroll
    for (int i = 0; i < 2; ++i)
      #pragma unroll
      for (int j = 0; j < 2; ++j)
        gf[i][j] = __builtin_amdgcn_mfma_f32_16x16x32_bf16(ca[i], bb[j], gf[i][j], 0, 0, 0);
  }
  // ---- M = G * exp(la_t - la_s) * dt_s, causal mask ----
  #pragma unroll
  for (int i = 0; i < 2; ++i) {
    #pragma unroll
    for (int j = 0; j < 2; ++j) {
      int s = (wc << 5) + (j << 4) + fr;
      float la_s = laS[s], dt_s = dtS[s];
      #pragma unroll
      for (int rr = 0; rr < 4; ++rr) {
        int t = (wr << 5) + (i << 4) + (g << 2) + rr;
        float e = __expf(fminf(laS[t] - la_s, 0.f));
        float val = (s <= t) ? gf[i][j][rr] * e * dt_s : 0.f;
        Ms[t][s] = f2bf(val);
      }
    }
  }
  __syncthreads();

  // ---- Y = M @ X, dh = BT @ X ----
  f32x4 yf[2][2], hf[2][2];
  #pragma unroll
  for (int i = 0; i < 2; ++i)
    #pragma unroll
    for (int j = 0; j < 2; ++j) { yf[i][j] = (f32x4){0.f,0.f,0.f,0.f}; hf[i][j] = (f32x4){0.f,0.f,0.f,0.f}; }
  #pragma unroll
  for (int ks = 0; ks < 2; ++ks) {
    bf16x8 ma[2], ba[2], xb[2];
    #pragma unroll
    for (int i = 0; i < 2; ++i) {
      ma[i] = *(const bf16x8*)&Ms[(wr << 5) + (i << 4) + fr][(ks << 5) + (g << 3)];
      ba[i] = *(const bf16x8*)&BT[(wr << 5) + (i << 4) + fr][(ks << 5) + (g << 3)];
    }
    #pragma unroll
    for (int j = 0; j < 2; ++j) xb[j] = *(const bf16x8*)&XT[(wc << 5) + (j << 4) + fr][(ks << 5) + (g << 3)];
    #pragma unroll
    for (int i = 0; i < 2; ++i)
      #pragma unroll
      for (int j = 0; j < 2; ++j) {
        yf[i][j] = __builtin_amdgcn_mfma_f32_16x16x32_bf16(ma[i], xb[j], yf[i][j], 0, 0, 0);
        hf[i][j] = __builtin_amdgcn_mfma_f32_16x16x32_bf16(ba[i], xb[j], hf[i][j], 0, 0, 0);
      }
  }
  float* dhb = dhbuf + ((size_t)(((c << 2) + b) * 32 + h) << 12);
  #pragma unroll
  for (int i = 0; i < 2; ++i) {
    #pragma unroll
    for (int j = 0; j < 2; ++j) {
      int p = (wc << 5) + (j << 4) + fr;
      #pragma unroll
      for (int rr = 0; rr < 4; ++rr) {
        int t = (wr << 5) + (i << 4) + (g << 2) + rr;
        ydin[((rowbase + t) << 11) + (h << 6) + p] = yf[i][j][rr];
        dhb[(t << 6) + p] = hf[i][j][rr];      // row index here is n
      }
    }
  }
}

// ---------- SSD stage 2: sequential over 16 chunks (elementwise) ----------
__global__ __launch_bounds__(256) void ssd2_k(const float* __restrict__ dhbuf,
    const float* __restrict__ labuf, float* __restrict__ hseq) {
  int idx = blockIdx.x * 256 + threadIdx.x;   // 524288 = b*h*n*p
  int np = idx & 4095;
  int h = (idx >> 12) & 31, b = idx >> 17;
  float carry = 0.f;
  #pragma unroll
  for (int c = 0; c < 16; ++c) {
    size_t o = ((size_t)(((c << 2) + b) * 32 + h) << 12) + np;
    hseq[o] = carry;
    float ec = __expf(labuf[(size_t)((((b << 4) | c) << 5 | h) << 6) + 63]);
    carry = fmaf(ec, carry, dhbuf[o]);
  }
}

// ---------- SSD stage 3: Y += exp(la_t) * C @ h_in + D*x ----------
__global__ __launch_bounds__(256) void ssd3_k(const float* __restrict__ xbc,
    const float* __restrict__ hseq, const float* __restrict__ labuf,
    const float* __restrict__ Dv, float* __restrict__ ydin) {
  __shared__ unsigned short Cs[64][68];   // [t][n]
  __shared__ unsigned short HT[64][68];   // [p][n]
  __shared__ float laS[64];
  const int id = blockIdx.x;
  const int h = id & 31, b = (id >> 5) & 3, c = id >> 7;
  const int tid = threadIdx.x, w = tid >> 6, lane = tid & 63;
  const int fr = lane & 15, g = lane >> 4;
  const size_t rowbase = (size_t)((b << 10) + (c << 6));
  {
    int r = tid >> 2, c0 = (tid & 3) << 4;
    const float* src = xbc + (rowbase + r) * 2176 + 2112 + c0;
    #pragma unroll
    for (int i = 0; i < 4; ++i) {
      float4 v = *(const float4*)(src + 4 * i);
      *(ushort4*)&Cs[r][c0 + 4 * i] = make_ushort4(f2bf(v.x), f2bf(v.y), f2bf(v.z), f2bf(v.w));
    }
  }
  {
    const float* hb = hseq + ((size_t)(((c << 2) + b) * 32 + h) << 12);
    int n0 = (tid & 15) << 2, p0 = (tid >> 4) << 2;
    float4 v0 = *(const float4*)(hb + ((n0 + 0) << 6) + p0);
    float4 v1 = *(const float4*)(hb + ((n0 + 1) << 6) + p0);
    float4 v2 = *(const float4*)(hb + ((n0 + 2) << 6) + p0);
    float4 v3 = *(const float4*)(hb + ((n0 + 3) << 6) + p0);
    *(ushort4*)&HT[p0 + 0][n0] = make_ushort4(f2bf(v0.x), f2bf(v1.x), f2bf(v2.x), f2bf(v3.x));
    *(ushort4*)&HT[p0 + 1][n0] = make_ushort4(f2bf(v0.y), f2bf(v1.y), f2bf(v2.y), f2bf(v3.y));
    *(ushort4*)&HT[p0 + 2][n0] = make_ushort4(f2bf(v0.z), f2bf(v1.z), f2bf(v2.z), f2bf(v3.z));
    *(ushort4*)&HT[p0 + 3][n0] = make_ushort4(f2bf(v0.w), f2bf(v1.w), f2bf(v2.w), f2bf(v3.w));
  }
  if (tid < 64) laS[tid] = labuf[(size_t)((((b << 4) | c) << 5 | h) << 6) + tid];
  __syncthreads();
  const int wr = w >> 1, wc = w & 1;
  f32x4 yf[2][2];
  #pragma unroll
  for (int i = 0; i < 2; ++i)
    #pragma unroll
    for (int j = 0; j < 2; ++j) yf[i][j] = (f32x4){0.f, 0.f, 0.f, 0.f};
  #pragma unroll
  for (int ks = 0; ks < 2; ++ks) {
    bf16x8 ca[2], hv[2];
    #pragma unroll
    for (int i = 0; i < 2; ++i) ca[i] = *(const bf16x8*)&Cs[(wr << 5) + (i << 4) + fr][(ks << 5) + (g << 3)];
    #pragma unroll
    for (int j = 0; j < 2; ++j) hv[j] = *(const bf16x8*)&HT[(wc << 5) + (j << 4) + fr][(ks << 5) + (g << 3)];
    #pragma unroll
    for (int i = 0; i < 2; ++i)
      #pragma unroll
      for (int j = 0; j < 2; ++j)
        yf[i][j] = __builtin_amdgcn_mfma_f32_16x16x32_bf16(ca[i], hv[j], yf[i][j], 0, 0, 0);
  }
  float Dh = Dv[h];
  #pragma unroll
  for (int i = 0; i < 2; ++i) {
    #pragma unroll
    for (int j = 0; j < 2; ++j) {
      int p = (wc << 5) + (j << 4) + fr;
      #pragma unroll
      for (int rr = 0; rr < 4; ++rr) {
        int t = (wr << 5) + (i << 4) + (g << 2) + rr;
        size_t yo = ((rowbase + t) << 11) + (h << 6) + p;
        float xv = xbc[(rowbase + t) * 2176 + (h << 6) + p];
        ydin[yo] = ydin[yo] + __expf(laS[t]) * yf[i][j][rr] + Dh * xv;
      }
    }
  }
}

// ---------- g = ydin * silu(z); rmsnorm(2048) * mnorm_w -> bf16 ----------
__global__ __launch_bounds__(256) void gnormk(const float* __restrict__ ydin,
    const unsigned short* __restrict__ zbf, const float* __restrict__ mw,
    unsigned short* __restrict__ gbf) {
  int row = blockIdx.x, tid = threadIdx.x;
  size_t base = ((size_t)row << 11) + ((size_t)tid << 3);
  float4 y0 = *(const float4*)(ydin + base);
  float4 y1 = *(const float4*)(ydin + base + 4);
  ushort4 z0 = *(const ushort4*)(zbf + base);
  ushort4 z1 = *(const ushort4*)(zbf + base + 4);
  float g[8];
  {
    float z;
    z = bf2f(z0.x); g[0] = y0.x * (z / (1.f + __expf(-z)));
    z = bf2f(z0.y); g[1] = y0.y * (z / (1.f + __expf(-z)));
    z = bf2f(z0.z); g[2] = y0.z * (z / (1.f + __expf(-z)));
    z = bf2f(z0.w); g[3] = y0.w * (z / (1.f + __expf(-z)));
    z = bf2f(z1.x); g[4] = y1.x * (z / (1.f + __expf(-z)));
    z = bf2f(z1.y); g[5] = y1.y * (z / (1.f + __expf(-z)));
    z = bf2f(z1.z); g[6] = y1.z * (z / (1.f + __expf(-z)));
    z = bf2f(z1.w); g[7] = y1.w * (z / (1.f + __expf(-z)));
  }
  float ss = 0.f;
  #pragma unroll
  for (int k = 0; k < 8; ++k) ss += g[k] * g[k];
  #pragma unroll
  for (int off = 32; off; off >>= 1) ss += __shfl_xor(ss, off);
  __shared__ float ws4[4];
  if ((tid & 63) == 0) ws4[tid >> 6] = ss;
  __syncthreads();
  float tot = ws4[0] + ws4[1] + ws4[2] + ws4[3];
  float sc = rsqrtf(tot * (1.f / 2048.f) + 1e-5f);
  int c0 = tid << 3;
  float4 m0 = *(const float4*)(mw + c0);
  float4 m1 = *(const float4*)(mw + c0 + 4);
  *(ushort4*)(gbf + base)     = make_ushort4(f2bf(g[0]*sc*m0.x), f2bf(g[1]*sc*m0.y), f2bf(g[2]*sc*m0.z), f2bf(g[3]*sc*m0.w));
  *(ushort4*)(gbf + base + 4) = make_ushort4(f2bf(g[4]*sc*m1.x), f2bf(g[5]*sc*m1.y), f2bf(g[6]*sc*m1.z), f2bf(g[7]*sc*m1.w));
}

// ---------- MQA causal attention (MFMA flash), out bf16 ----------
__global__ __launch_bounds__(256) void attnk(const float* __restrict__ qkv,
                                             unsigned short* __restrict__ ybf) {
  __shared__ unsigned short Qs[64][72];
  __shared__ unsigned short Ks[64][72];
  __shared__ unsigned short VT[64][72];   // VT[d][key]
  __shared__ unsigned short Ps[4][16][72];
  const int id = blockIdx.x;
  const int b = id & 3, h = (id >> 2) & 15, qt = id >> 6;
  const int t0 = qt << 6;
  const int tid = threadIdx.x, w = tid >> 6, lane = tid & 63;
  const int fr = lane & 15, g = lane >> 4;
  {
    int r = tid >> 2, d0 = (tid & 3) << 4;
    const float* src = qkv + ((size_t)((b << 10) | (t0 + r))) * 1152 + (h << 6) + d0;
    #pragma unroll
    for (int i = 0; i < 4; ++i) {
      float4 v = *(const float4*)(src + 4 * i);
      *(ushort4*)&Qs[r][d0 + 4 * i] =
          make_ushort4(f2bf(v.x * 0.125f), f2bf(v.y * 0.125f), f2bf(v.z * 0.125f), f2bf(v.w * 0.125f));
    }
  }
  __syncthreads();
  bf16x8 afQ0 = *(const bf16x8*)&Qs[(w << 4) + fr][g << 3];
  bf16x8 afQ1 = *(const bf16x8*)&Qs[(w << 4) + fr][32 + (g << 3)];
  f32x4 acc_o[4];
  #pragma unroll
  for (int i = 0; i < 4; ++i) acc_o[i] = (f32x4){0.f, 0.f, 0.f, 0.f};
  float m[4] = {-1e30f, -1e30f, -1e30f, -1e30f};
  float l[4] = {0.f, 0.f, 0.f, 0.f};
  const int qrow = t0 + (w << 4) + (g << 2);
  for (int kt = 0; kt <= qt; ++kt) {
    const int s0 = kt << 6;
    __syncthreads();
    {
      int r = tid >> 2, d0 = (tid & 3) << 4;
      const float* src = qkv + ((size_t)((b << 10) | (s0 + r))) * 1152 + 1024 + d0;
      #pragma unroll
      for (int i = 0; i < 4; ++i) {
        float4 v = *(const float4*)(src + 4 * i);
        *(ushort4*)&Ks[r][d0 + 4 * i] = make_ushort4(f2bf(v.x), f2bf(v.y), f2bf(v.z), f2bf(v.w));
      }
    }
    {
      int r0 = (tid & 15) << 2, d0 = (tid >> 4) << 2;
      const float* src = qkv + ((size_t)((b << 10) | (s0 + r0))) * 1152 + 1088 + d0;
      float4 v0 = *(const float4*)(src);
      float4 v1 = *(const float4*)(src + 1152);
      float4 v2 = *(const float4*)(src + 2304);
      float4 v3 = *(const float4*)(src + 3456);
      *(ushort4*)&VT[d0 + 0][r0] = make_ushort4(f2bf(v0.x), f2bf(v1.x), f2bf(v2.x), f2bf(v3.x));
      *(ushort4*)&VT[d0 + 1][r0] = make_ushort4(f2bf(v0.y), f2bf(v1.y), f2bf(v2.y), f2bf(v3.y));
      *(ushort4*)&VT[d0 + 2][r0] = make_ushort4(f2bf(v0.z), f2bf(v1.z), f2bf(v2.z), f2bf(v3.z));
      *(ushort4*)&VT[d0 + 3][r0] = make_ushort4(f2bf(v0.w), f2bf(v1.w), f2bf(v2.w), f2bf(v3.w));
    }
    __syncthreads();
    f32x4 s4[4];
    #pragma unroll
    for (int jt = 0; jt < 4; ++jt) {
      bf16x8 b0 = *(const bf16x8*)&Ks[(jt << 4) + fr][g << 3];
      bf16x8 b1 = *(const bf16x8*)&Ks[(jt << 4) + fr][32 + (g << 3)];
      f32x4 z4 = (f32x4){0.f, 0.f, 0.f, 0.f};
      z4 = __builtin_amdgcn_mfma_f32_16x16x32_bf16(afQ0, b0, z4, 0, 0, 0);
      z4 = __builtin_amdgcn_mfma_f32_16x16x32_bf16(afQ1, b1, z4, 0, 0, 0);
      s4[jt] = z4;
    }
    if (kt == qt) {
      #pragma unroll
      for (int jt = 0; jt < 4; ++jt) {
        int key = s0 + (jt << 4) + fr;
        #pragma unroll
        for (int r = 0; r < 4; ++r)
          if (key > qrow + r) s4[jt][r] = -1e30f;
      }
    }
    #pragma unroll
    for (int r = 0; r < 4; ++r) {
      float mt = fmaxf(fmaxf(s4[0][r], s4[1][r]), fmaxf(s4[2][r], s4[3][r]));
      #pragma unroll
      for (int off = 8; off; off >>= 1) mt = fmaxf(mt, __shfl_xor(mt, off));
      float mn = fmaxf(m[r], mt);
      float scl = __expf(m[r] - mn);
      m[r] = mn;
      float ps = 0.f;
      #pragma unroll
      for (int jt = 0; jt < 4; ++jt) {
        float p = __expf(s4[jt][r] - mn);
        ps += p;
        Ps[w][(g << 2) + r][(jt << 4) + fr] = f2bf(p);
      }
      #pragma unroll
      for (int off = 8; off; off >>= 1) ps += __shfl_xor(ps, off);
      l[r] = l[r] * scl + ps;
      acc_o[0][r] *= scl; acc_o[1][r] *= scl; acc_o[2][r] *= scl; acc_o[3][r] *= scl;
    }
    #pragma unroll
    for (int ks = 0; ks < 2; ++ks) {
      bf16x8 ap = *(const bf16x8*)&Ps[w][fr][(ks << 5) + (g << 3)];
      #pragma unroll
      for (int dt = 0; dt < 4; ++dt) {
        bf16x8 bv = *(const bf16x8*)&VT[(dt << 4) + fr][(ks << 5) + (g << 3)];
        acc_o[dt] = __builtin_amdgcn_mfma_f32_16x16x32_bf16(ap, bv, acc_o[dt], 0, 0, 0);
      }
    }
  }
  #pragma unroll
  for (int dt = 0; dt < 4; ++dt) {
    #pragma unroll
    for (int r = 0; r < 4; ++r) {
      float o = acc_o[dt][r] / l[r];
      int t = t0 + (w << 4) + (g << 2) + r;
      ybf[(((size_t)((b << 10) | t)) << 10) + (h << 6) + (dt << 4) + fr] = f2bf(o);
    }
  }
}

// ---------- cmix token-shift mix -> xk, xr (bf16) ----------
__global__ __launch_bounds__(256) void mixk(const float* __restrict__ xn3,
    const float* __restrict__ tmk, const float* __restrict__ tmr,
    unsigned short* __restrict__ xkbf, unsigned short* __restrict__ xrbf) {
  int idx4 = blockIdx.x * 256 + threadIdx.x;
  int col = (idx4 & 255) << 2;
  int row = idx4 >> 8;
  int t = row & 1023;
  size_t off = ((size_t)idx4) << 2;
  float4 cur = *(const float4*)(xn3 + off);
  float4 prev = make_float4(0.f, 0.f, 0.f, 0.f);
  if (t > 0) prev = *(const float4*)(xn3 + off - 1024);
  float4 tk = *(const float4*)(tmk + col);
  float4 tr = *(const float4*)(tmr + col);
  float dx = prev.x - cur.x, dy = prev.y - cur.y, dz = prev.z - cur.z, dw = prev.w - cur.w;
  *(ushort4*)(xkbf + off) = make_ushort4(
      f2bf(cur.x + dx * tk.x), f2bf(cur.y + dy * tk.y), f2bf(cur.z + dz * tk.z), f2bf(cur.w + dw * tk.w));
  *(ushort4*)(xrbf + off) = make_ushort4(
      f2bf(cur.x + dx * tr.x), f2bf(cur.y + dy * tr.y), f2bf(cur.z + dz * tr.z), f2bf(cur.w + dw * tr.w));
}

// ---------- final: out = x2 + sigmoid(rraw) * vout ----------
__global__ __launch_bounds__(256) void finalk(const float* __restrict__ x2,
    const float* __restrict__ rraw, const float* __restrict__ vout,
    float* __restrict__ out) {
  int idx4 = blockIdx.x * 256 + threadIdx.x;
  size_t off = ((size_t)idx4) << 2;
  float4 xv = *(const float4*)(x2 + off);
  float4 rv = *(const float4*)(rraw + off);
  float4 vv = *(const float4*)(vout + off);
  float4 o;
  o.x = xv.x + vv.x / (1.f + __expf(-rv.x));
  o.y = xv.y + vv.y / (1.f + __expf(-rv.y));
  o.z = xv.z + vv.z / (1.f + __expf(-rv.z));
  o.w = xv.w + vv.w / (1.f + __expf(-rv.w));
  *(float4*)(out + off) = o;
}

// ---------- host launcher ----------
extern "C" void kernel_launch(void* const* d_in, const int* in_sizes, int n_in,
                              void* d_out, int out_size, void* d_ws, size_t ws_size,
                              hipStream_t stream) {
  (void)in_sizes; (void)n_in; (void)out_size;
  const float* x        = (const float*)d_in[0];
  const float* in_proj  = (const float*)d_in[1];
  const float* conv_w   = (const float*)d_in[2];
  const float* conv_b   = (const float*)d_in[3];
  const float* dt_bias  = (const float*)d_in[4];
  const float* A_log    = (const float*)d_in[5];
  const float* Dvec     = (const float*)d_in[6];
  const float* mnorm_w  = (const float*)d_in[7];
  const float* out_proj = (const float*)d_in[8];
  const float* attn_w   = (const float*)d_in[9];
  const float* proj_w   = (const float*)d_in[10];
  const float* tmk      = (const float*)d_in[11];
  const float* tmr      = (const float*)d_in[12];
  const float* key_w    = (const float*)d_in[13];
  const float* recept_w = (const float*)d_in[14];
  const float* value_w  = (const float*)d_in[15];
  float* out = (float*)d_out;

  if (ws_size < 199229440ull) return;

  char* ws = (char*)d_ws;
  unsigned short* Wt   = (unsigned short*)(ws + 0);
  unsigned short* Abf  = (unsigned short*)(ws + 8912896ull);    // xn1/xn2/atty/kact; hseq(f32) during SSD; g
  unsigned short* Abf2 = (unsigned short*)(ws + 42467328ull);   // z | xk,xr
  float* bigF = (float*)(ws + 59244544ull);                     // zxbcdt [4096][2208]; dhbuf during SSD
  float* big1 = (float*)(ws + 95420416ull);                     // xbc / mo / qkv / rraw
  float* big2 = (float*)(ws + 131072000ull);                    // ydin / po / vout
  float* x1   = (float*)(ws + 164626432ull);
  float* xn3  = (float*)(ws + 181403648ull);
  float* dtb  = (float*)(ws + 198180864ull);
  float* labuf= (float*)(ws + 198705152ull);
  unsigned short* zbf  = Abf2;
  unsigned short* xkbf = Abf2;
  unsigned short* xrbf = Abf2 + 4194304;
  float* dhbuf = bigF;            // 33.5 MB, zxbcdt dead by then
  float* hseq  = (float*)Abf;     // 33.5 MB, xn1 dead by then

  dim3 b256(256);
  dim3 tb(32, 8);

  // ===== Phase A: mamba2 =====
  resrms_k<0, 0, 0><<<4096, b256, 0, stream>>>(x, nullptr, nullptr, Abf, nullptr);
  transp_k<<<dim3(64, 32), tb, 0, stream>>>(in_proj, Wt, 1024, 2048, 2048, 0, 4256);
  gemm_k<1><<<dim3(16, 32), b256, 0, stream>>>(Abf, Wt, zbf, 4096, 2048, 1024);          // z (bf16)
  transp_k<<<dim3(72, 32), tb, 0, stream>>>(in_proj, Wt, 1024, 2208, 2304, 2048, 4256);
  gemm_k<0><<<dim3(18, 32), b256, 0, stream>>>(Abf, Wt, bigF, 4096, 2208, 1024);         // xBC+dt (f32)
  dtk<<<512, b256, 0, stream>>>(bigF, dt_bias, dtb);
  convk<<<34816, b256, 0, stream>>>(bigF, conv_w, conv_b, big1);                         // xbc_act
  ssd1_k<<<2048, b256, 0, stream>>>(big1, dtb, A_log, big2, dhbuf, labuf);               // Y_intra, dh, la
  ssd2_k<<<2048, b256, 0, stream>>>(dhbuf, labuf, hseq);                                 // chunk states
  ssd3_k<<<2048, b256, 0, stream>>>(big1, hseq, labuf, Dvec, big2);                      // ydin final
  gnormk<<<4096, b256, 0, stream>>>(big2, zbf, mnorm_w, Abf);                            // g (bf16)
  transp_k<<<dim3(32, 64), tb, 0, stream>>>(out_proj, Wt, 2048, 1024, 1024, 0, 1024);
  gemm_k<0><<<dim3(8, 32), b256, 0, stream>>>(Abf, Wt, big1, 4096, 1024, 2048);          // mo
  resrms_k<1, 1, 0><<<4096, b256, 0, stream>>>(x, big1, x1, Abf, nullptr);               // x1, xn2

  // ===== Phase B: mqa =====
  transp_k<<<dim3(36, 32), tb, 0, stream>>>(attn_w, Wt, 1024, 1152, 1152, 0, 1152);
  gemm_k<0><<<dim3(9, 32), b256, 0, stream>>>(Abf, Wt, big1, 4096, 1152, 1024);          // qkv
  attnk<<<1024, b256, 0, stream>>>(big1, Abf);                                           // atty (bf16)
  transp_k<<<dim3(32, 32), tb, 0, stream>>>(proj_w, Wt, 1024, 1024, 1024, 0, 1024);
  gemm_k<0><<<dim3(8, 32), b256, 0, stream>>>(Abf, Wt, big2, 4096, 1024, 1024);          // po
  resrms_k<1, 1, 1><<<4096, b256, 0, stream>>>(x1, big2, x1, Abf, xn3);                  // x2 (in x1), xn3

  // ===== Phase C: cmix =====
  mixk<<<4096, b256, 0, stream>>>(xn3, tmk, tmr, xkbf, xrbf);
  transp_k<<<dim3(128, 32), tb, 0, stream>>>(key_w, Wt, 1024, 4096, 4096, 0, 4096);
  gemm_k<2><<<dim3(32, 32), b256, 0, stream>>>(xkbf, Wt, Abf, 4096, 4096, 1024);         // kact (bf16)
  transp_k<<<dim3(32, 128), tb, 0, stream>>>(value_w, Wt, 4096, 1024, 1024, 0, 1024);
  gemm_k<0><<<dim3(8, 32), b256, 0, stream>>>(Abf, Wt, big2, 4096, 1024, 4096);          // vout
  transp_k<<<dim3(32, 32), tb, 0, stream>>>(recept_w, Wt, 1024, 1024, 1024, 0, 1024);
  gemm_k<0><<<dim3(8, 32), b256, 0, stream>>>(xrbf, Wt, big1, 4096, 1024, 1024);         // rraw
  finalk<<<4096, b256, 0, stream>>>(x1, big1, big2, out);
}

// Round 4
// 528.992 us; speedup vs baseline: 2.6866x; 1.1961x over previous
//
#include <hip/hip_runtime.h>

// ---------- helpers ----------
__device__ __forceinline__ unsigned short f2bf(float f) {
  unsigned u = __builtin_bit_cast(unsigned, f);
  u = u + 0x7fffu + ((u >> 16) & 1u);      // RNE
  return (unsigned short)(u >> 16);
}
__device__ __forceinline__ float bf2f(unsigned short u) {
  return __builtin_bit_cast(float, ((unsigned)u) << 16);
}

typedef __bf16 bf16x8 __attribute__((ext_vector_type(8)));
typedef float  f32x4  __attribute__((ext_vector_type(4)));

#define GLD16(gp, lp) __builtin_amdgcn_global_load_lds( \
    (const __attribute__((address_space(1))) unsigned int*)(gp), \
    (__attribute__((address_space(3))) unsigned int*)(lp), 16, 0, 0)

// ---------- rmsnorm (+ optional residual) ----------
template<int HAS_DELTA, int WRITE_SUM, int WRITE_N32>
__global__ __launch_bounds__(256) void resrms_k(const float* __restrict__ xin,
    const float* __restrict__ delta, float* __restrict__ xsum,
    unsigned short* __restrict__ nbf, float* __restrict__ nf32) {
  int row = blockIdx.x, tid = threadIdx.x;
  size_t base = ((size_t)row << 10) + ((size_t)tid << 2);
  float4 v = *(const float4*)(xin + base);
  if (HAS_DELTA) {
    float4 d = *(const float4*)(delta + base);
    v.x += d.x; v.y += d.y; v.z += d.z; v.w += d.w;
  }
  if (WRITE_SUM) *(float4*)(xsum + base) = v;
  float ss = v.x*v.x + v.y*v.y + v.z*v.z + v.w*v.w;
  #pragma unroll
  for (int off = 32; off; off >>= 1) ss += __shfl_xor(ss, off);
  __shared__ float ws4[4];
  if ((tid & 63) == 0) ws4[tid >> 6] = ss;
  __syncthreads();
  float tot = ws4[0] + ws4[1] + ws4[2] + ws4[3];
  float sc = rsqrtf(tot * (1.0f / 1024.0f) + 1e-5f);
  *(ushort4*)(nbf + base) = make_ushort4(f2bf(v.x*sc), f2bf(v.y*sc), f2bf(v.z*sc), f2bf(v.w*sc));
  if (WRITE_N32) {
    float4 n; n.x = v.x*sc; n.y = v.y*sc; n.z = v.z*sc; n.w = v.w*sc;
    *(float4*)(nf32 + base) = n;
  }
}

// ---------- transpose+convert: W[K][ldw] f32 -> Wt[Npad][K] bf16 ----------
__global__ void transp_k(const float* __restrict__ W, unsigned short* __restrict__ Wt,
                         int K, int Ncols, int Npad, int col_off, int ldw) {
  __shared__ float t[32][33];
  int n0 = blockIdx.x << 5, k0 = blockIdx.y << 5;
  int tx = threadIdx.x, ty = threadIdx.y;
  #pragma unroll
  for (int rr = 0; rr < 32; rr += 8) {
    int k = k0 + rr + ty, n = n0 + tx;
    t[rr + ty][tx] = (n < Ncols) ? W[(size_t)k * ldw + col_off + n] : 0.f;
  }
  __syncthreads();
  #pragma unroll
  for (int rr = 0; rr < 32; rr += 8) {
    int nrow = n0 + rr + ty;
    Wt[(size_t)nrow * K + k0 + tx] = f2bf(t[tx][rr + ty]);
  }
}

// ---------- bf16 MFMA GEMM, deep-pipelined: C[M][N] = A[M][K] * Bt[N][K]^T ----------
// BM=128, BN=256, BK=32, 512 threads = 8 waves (wave tile 64x64).
// 3 rotating LDS buffers, prefetch distance 2, counted vmcnt(3), raw s_barrier.
// LDS XOR swizzle: 16B chunk index ^= (row>>1)&3, applied on BOTH source addr and read.
// EPI: 0 = f32 store, 1 = bf16 store, 2 = erf-activation -> bf16 store
template<int EPI>
__global__ __launch_bounds__(512, 4) void gemm2_k(const unsigned short* __restrict__ A,
    const unsigned short* __restrict__ Bt, void* __restrict__ Cout,
    int M, int N, int K, int ntx) {
  __shared__ unsigned short lds2[3 * 12288];   // per buf: A 4096 sh + B 8192 sh = 24KB; x3 = 72KB
  const int tid = threadIdx.x;
  const int w = tid >> 6, lane = tid & 63;
  const int fr = lane & 15, g = lane >> 4;
  // XCD-aware bijective block swizzle (nwg always %8==0 here)
  const int nwg = gridDim.x;
  const int sid = (blockIdx.x & 7) * (nwg >> 3) + (blockIdx.x >> 3);
  const int by = sid / ntx, bx = sid - by * ntx;
  const int m0 = by << 7, n0 = bx << 8;
  const int wm = (w >> 2) << 6;       // 0 / 64
  const int wn = (w & 3) << 6;        // 0 / 64 / 128 / 192

  f32x4 acc[4][4];
  #pragma unroll
  for (int i = 0; i < 4; ++i)
    #pragma unroll
    for (int j = 0; j < 4; ++j) acc[i][j] = (f32x4){0.f, 0.f, 0.f, 0.f};

  // staging source (swizzled chunk): thread covers physical chunk-slot tid (A) / tid,tid+512 (B)
  const int srow = tid >> 2;                       // 0..127
  const int schunk = (tid & 3) ^ ((tid >> 3) & 3); // logical chunk fetched into physical slot
  const unsigned short* Asrc = A + (size_t)(m0 + srow) * K + (schunk << 3);
  const unsigned short* Bsrc = Bt + (size_t)(n0 + srow) * K + (schunk << 3);
  const size_t bskip = (size_t)128 * K;
  const int wofs = w << 9;   // wave-uniform LDS dest offset (shorts)

#define STAGE2(kt_, buf_) { \
    const unsigned short* ga_ = Asrc + ((kt_) << 5); \
    const unsigned short* gb_ = Bsrc + ((kt_) << 5); \
    GLD16(ga_, lds2 + (buf_) * 12288 + wofs); \
    GLD16(gb_, lds2 + (buf_) * 12288 + 4096 + wofs); \
    GLD16(gb_ + bskip, lds2 + (buf_) * 12288 + 8192 + wofs); }

  const int nt = K >> 5;
  STAGE2(0, 0)
  STAGE2(1, 1)
  asm volatile("s_waitcnt vmcnt(3)" ::: "memory");
  __builtin_amdgcn_s_barrier();
  __builtin_amdgcn_sched_barrier(0);

  const int coff = (g ^ ((fr >> 1) & 3)) << 3;  // swizzled in-row chunk offset (shorts)
  int cb = 0;
  for (int kt = 0; kt < nt; ++kt) {
    if (kt + 2 < nt) {
      int sb = cb + 2; if (sb >= 3) sb -= 3;
      STAGE2(kt + 2, sb)
    }
    const unsigned short* bufp = lds2 + cb * 12288;
    bf16x8 bfr[4];
    #pragma unroll
    for (int j = 0; j < 4; ++j)
      bfr[j] = *(const bf16x8*)&bufp[4096 + ((wn + (j << 4) + fr) << 5) + coff];
    bf16x8 a0 = *(const bf16x8*)&bufp[((wm + fr) << 5) + coff];
    bf16x8 a1 = *(const bf16x8*)&bufp[((wm + 16 + fr) << 5) + coff];
    __builtin_amdgcn_s_setprio(1);
    #pragma unroll
    for (int j = 0; j < 4; ++j) acc[0][j] = __builtin_amdgcn_mfma_f32_16x16x32_bf16(a0, bfr[j], acc[0][j], 0, 0, 0);
    #pragma unroll
    for (int j = 0; j < 4; ++j) acc[1][j] = __builtin_amdgcn_mfma_f32_16x16x32_bf16(a1, bfr[j], acc[1][j], 0, 0, 0);
    __builtin_amdgcn_s_setprio(0);
    bf16x8 a2 = *(const bf16x8*)&bufp[((wm + 32 + fr) << 5) + coff];
    bf16x8 a3 = *(const bf16x8*)&bufp[((wm + 48 + fr) << 5) + coff];
    __builtin_amdgcn_s_setprio(1);
    #pragma unroll
    for (int j = 0; j < 4; ++j) acc[2][j] = __builtin_amdgcn_mfma_f32_16x16x32_bf16(a2, bfr[j], acc[2][j], 0, 0, 0);
    #pragma unroll
    for (int j = 0; j < 4; ++j) acc[3][j] = __builtin_amdgcn_mfma_f32_16x16x32_bf16(a3, bfr[j], acc[3][j], 0, 0, 0);
    __builtin_amdgcn_s_setprio(0);
    if (kt + 1 < nt) {
      if (kt + 2 < nt) { asm volatile("s_waitcnt vmcnt(3)" ::: "memory"); }
      else            { asm volatile("s_waitcnt vmcnt(0)" ::: "memory"); }
      __builtin_amdgcn_s_barrier();
      __builtin_amdgcn_sched_barrier(0);
    }
    cb = cb + 1; if (cb >= 3) cb -= 3;
  }
#undef STAGE2

  const int rin = g << 2;
  #pragma unroll
  for (int i = 0; i < 4; ++i) {
    #pragma unroll
    for (int j = 0; j < 4; ++j) {
      int col = n0 + wn + (j << 4) + fr;
      if (col < N) {
        #pragma unroll
        for (int rr = 0; rr < 4; ++rr) {
          int row = m0 + wm + (i << 4) + rin + rr;
          float v = acc[i][j][rr];
          if (EPI == 0) {
            ((float*)Cout)[(size_t)row * N + col] = v;
          } else if (EPI == 1) {
            ((unsigned short*)Cout)[(size_t)row * N + col] = f2bf(v);
          } else {
            float kv = 0.5f * (1.0f + erff((v - 0.70710678f) * 2.5066283f));
            ((unsigned short*)Cout)[(size_t)row * N + col] = f2bf(kv);
          }
        }
      }
    }
  }
}

// ---------- dt ----------
__global__ __launch_bounds__(256) void dtk(const float* __restrict__ zxr,
    const float* __restrict__ dt_bias, float* __restrict__ dt) {
  int i = blockIdx.x * 256 + threadIdx.x;     // 4096*32
  int r = i >> 5, hh = i & 31;
  float v = zxr[(size_t)r * 2208 + 2176 + hh] + dt_bias[hh];
  float dtv = (v > 20.f) ? v : log1pf(__expf(v));
  dt[i] = dtv;
}

// ---------- causal depthwise conv(4) + silu ----------
__global__ __launch_bounds__(256) void convk(const float* __restrict__ zxr,
    const float* __restrict__ conv_w, const float* __restrict__ conv_b,
    float* __restrict__ xbc) {
  int i = blockIdx.x * 256 + threadIdx.x;     // 4*1024*2176
  if (i >= 4 * 1024 * 2176) return;
  int c = i % 2176; int bt = i / 2176; int t = bt & 1023;
  const float* col = zxr + (size_t)bt * 2208 + c;
  float acc = conv_b[c];
  float w0 = conv_w[c * 4 + 0], w1 = conv_w[c * 4 + 1], w2 = conv_w[c * 4 + 2], w3 = conv_w[c * 4 + 3];
  if (t >= 3) acc = fmaf(col[-3 * 2208], w0, acc);
  if (t >= 2) acc = fmaf(col[-2 * 2208], w1, acc);
  if (t >= 1) acc = fmaf(col[-1 * 2208], w2, acc);
  acc = fmaf(col[0], w3, acc);
  xbc[(size_t)bt * 2176 + c] = acc / (1.f + __expf(-acc));
}

// ---------- SSD chunked scan, stage 1 ----------
__global__ __launch_bounds__(256) void ssd1_k(const float* __restrict__ xbc,
    const float* __restrict__ dtb, const float* __restrict__ A_log,
    float* __restrict__ ydin, float* __restrict__ dhbuf, float* __restrict__ labuf) {
  __shared__ unsigned short Cs[64][68];   // [t][d]
  __shared__ unsigned short Bsm[64][68];  // [s][d]
  __shared__ unsigned short XT[64][68];   // [p][s]
  __shared__ unsigned short BT[64][68];   // [n][s] (scaled)
  __shared__ unsigned short Ms[64][68];   // [t][s]
  __shared__ float laS[64], dtS[64];
  const int id = blockIdx.x;
  const int h = id & 31, b = (id >> 5) & 3, c = id >> 7;
  const int tid = threadIdx.x, w = tid >> 6, lane = tid & 63;
  const int fr = lane & 15, g = lane >> 4;
  const size_t rowbase = (size_t)((b << 10) + (c << 6));

  {
    int r = tid >> 2, c0 = (tid & 3) << 4;
    const float* src = xbc + (rowbase + r) * 2176;
    #pragma unroll
    for (int i = 0; i < 4; ++i) {
      float4 v = *(const float4*)(src + 2112 + c0 + 4 * i);
      *(ushort4*)&Cs[r][c0 + 4 * i] = make_ushort4(f2bf(v.x), f2bf(v.y), f2bf(v.z), f2bf(v.w));
      float4 u = *(const float4*)(src + 2048 + c0 + 4 * i);
      *(ushort4*)&Bsm[r][c0 + 4 * i] = make_ushort4(f2bf(u.x), f2bf(u.y), f2bf(u.z), f2bf(u.w));
    }
  }
  {
    int r0 = (tid & 15) << 2, d0 = (tid >> 4) << 2;
    const float* src = xbc + (rowbase + r0) * 2176 + (h << 6) + d0;
    float4 v0 = *(const float4*)(src);
    float4 v1 = *(const float4*)(src + 2176);
    float4 v2 = *(const float4*)(src + 4352);
    float4 v3 = *(const float4*)(src + 6528);
    *(ushort4*)&XT[d0 + 0][r0] = make_ushort4(f2bf(v0.x), f2bf(v1.x), f2bf(v2.x), f2bf(v3.x));
    *(ushort4*)&XT[d0 + 1][r0] = make_ushort4(f2bf(v0.y), f2bf(v1.y), f2bf(v2.y), f2bf(v3.y));
    *(ushort4*)&XT[d0 + 2][r0] = make_ushort4(f2bf(v0.z), f2bf(v1.z), f2bf(v2.z), f2bf(v3.z));
    *(ushort4*)&XT[d0 + 3][r0] = make_ushort4(f2bf(v0.w), f2bf(v1.w), f2bf(v2.w), f2bf(v3.w));
  }
  if (w == 0) {
    float Ah = -__expf(A_log[h]);
    float dtv = dtb[(rowbase + lane) * 32 + h];
    float v = dtv * Ah;
    #pragma unroll
    for (int off = 1; off < 64; off <<= 1) {
      float u = __shfl_up(v, off);
      if (lane >= off) v += u;
    }
    laS[lane] = v; dtS[lane] = dtv;
    labuf[(size_t)((((b << 4) | c) << 5 | h) << 6) + lane] = v;
  }
  __syncthreads();

  const int wr = w >> 1, wc = w & 1;
  f32x4 gf[2][2];
  #pragma unroll
  for (int i = 0; i < 2; ++i)
    #pragma unroll
    for (int j = 0; j < 2; ++j) gf[i][j] = (f32x4){0.f, 0.f, 0.f, 0.f};
  {
    int r0 = (tid & 15) << 2, d0 = (tid >> 4) << 2;
    const float* src = xbc + (rowbase + r0) * 2176 + 2048 + d0;
    float la63 = laS[63];
    float4 v0 = *(const float4*)(src);
    float4 v1 = *(const float4*)(src + 2176);
    float4 v2 = *(const float4*)(src + 4352);
    float4 v3 = *(const float4*)(src + 6528);
    float w0 = __expf(la63 - laS[r0 + 0]) * dtS[r0 + 0];
    float w1 = __expf(la63 - laS[r0 + 1]) * dtS[r0 + 1];
    float w2 = __expf(la63 - laS[r0 + 2]) * dtS[r0 + 2];
    float w3 = __expf(la63 - laS[r0 + 3]) * dtS[r0 + 3];
    *(ushort4*)&BT[d0 + 0][r0] = make_ushort4(f2bf(v0.x*w0), f2bf(v1.x*w1), f2bf(v2.x*w2), f2bf(v3.x*w3));
    *(ushort4*)&BT[d0 + 1][r0] = make_ushort4(f2bf(v0.y*w0), f2bf(v1.y*w1), f2bf(v2.y*w2), f2bf(v3.y*w3));
    *(ushort4*)&BT[d0 + 2][r0] = make_ushort4(f2bf(v0.z*w0), f2bf(v1.z*w1), f2bf(v2.z*w2), f2bf(v3.z*w3));
    *(ushort4*)&BT[d0 + 3][r0] = make_ushort4(f2bf(v0.w*w0), f2bf(v1.w*w1), f2bf(v2.w*w2), f2bf(v3.w*w3));
  }
  #pragma unroll
  for (int ks = 0; ks < 2; ++ks) {
    bf16x8 ca[2], bb[2];
    #pragma unroll
    for (int i = 0; i < 2; ++i) ca[i] = *(const bf16x8*)&Cs[(wr << 5) + (i << 4) + fr][(ks << 5) + (g << 3)];
    #pragma unroll
    for (int j = 0; j < 2; ++j) bb[j] = *(const bf16x8*)&Bsm[(wc << 5) + (j << 4) + fr][(ks << 5) + (g << 3)];
    #pragma unroll
    for (int i = 0; i < 2; ++i)
      #pragma unroll
      for (int j = 0; j < 2; ++j)
        gf[i][j] = __builtin_amdgcn_mfma_f32_16x16x32_bf16(ca[i], bb[j], gf[i][j], 0, 0, 0);
  }
  #pragma unroll
  for (int i = 0; i < 2; ++i) {
    #pragma unroll
    for (int j = 0; j < 2; ++j) {
      int s = (wc << 5) + (j << 4) + fr;
      float la_s = laS[s], dt_s = dtS[s];
      #pragma unroll
      for (int rr = 0; rr < 4; ++rr) {
        int t = (wr << 5) + (i << 4) + (g << 2) + rr;
        float e = __expf(fminf(laS[t] - la_s, 0.f));
        float val = (s <= t) ? gf[i][j][rr] * e * dt_s : 0.f;
        Ms[t][s] = f2bf(val);
      }
    }
  }
  __syncthreads();

  f32x4 yf[2][2], hf[2][2];
  #pragma unroll
  for (int i = 0; i < 2; ++i)
    #pragma unroll
    for (int j = 0; j < 2; ++j) { yf[i][j] = (f32x4){0.f,0.f,0.f,0.f}; hf[i][j] = (f32x4){0.f,0.f,0.f,0.f}; }
  #pragma unroll
  for (int ks = 0; ks < 2; ++ks) {
    bf16x8 ma[2], ba[2], xb[2];
    #pragma unroll
    for (int i = 0; i < 2; ++i) {
      ma[i] = *(const bf16x8*)&Ms[(wr << 5) + (i << 4) + fr][(ks << 5) + (g << 3)];
      ba[i] = *(const bf16x8*)&BT[(wr << 5) + (i << 4) + fr][(ks << 5) + (g << 3)];
    }
    #pragma unroll
    for (int j = 0; j < 2; ++j) xb[j] = *(const bf16x8*)&XT[(wc << 5) + (j << 4) + fr][(ks << 5) + (g << 3)];
    #pragma unroll
    for (int i = 0; i < 2; ++i)
      #pragma unroll
      for (int j = 0; j < 2; ++j) {
        yf[i][j] = __builtin_amdgcn_mfma_f32_16x16x32_bf16(ma[i], xb[j], yf[i][j], 0, 0, 0);
        hf[i][j] = __builtin_amdgcn_mfma_f32_16x16x32_bf16(ba[i], xb[j], hf[i][j], 0, 0, 0);
      }
  }
  float* dhb = dhbuf + ((size_t)(((c << 2) + b) * 32 + h) << 12);
  #pragma unroll
  for (int i = 0; i < 2; ++i) {
    #pragma unroll
    for (int j = 0; j < 2; ++j) {
      int p = (wc << 5) + (j << 4) + fr;
      #pragma unroll
      for (int rr = 0; rr < 4; ++rr) {
        int t = (wr << 5) + (i << 4) + (g << 2) + rr;
        ydin[((rowbase + t) << 11) + (h << 6) + p] = yf[i][j][rr];
        dhb[(t << 6) + p] = hf[i][j][rr];
      }
    }
  }
}

// ---------- SSD stage 2 ----------
__global__ __launch_bounds__(256) void ssd2_k(const float* __restrict__ dhbuf,
    const float* __restrict__ labuf, float* __restrict__ hseq) {
  int idx = blockIdx.x * 256 + threadIdx.x;   // 524288 = b*h*n*p
  int np = idx & 4095;
  int h = (idx >> 12) & 31, b = idx >> 17;
  float carry = 0.f;
  #pragma unroll
  for (int c = 0; c < 16; ++c) {
    size_t o = ((size_t)(((c << 2) + b) * 32 + h) << 12) + np;
    hseq[o] = carry;
    float ec = __expf(labuf[(size_t)((((b << 4) | c) << 5 | h) << 6) + 63]);
    carry = fmaf(ec, carry, dhbuf[o]);
  }
}

// ---------- SSD stage 3 ----------
__global__ __launch_bounds__(256) void ssd3_k(const float* __restrict__ xbc,
    const float* __restrict__ hseq, const float* __restrict__ labuf,
    const float* __restrict__ Dv, float* __restrict__ ydin) {
  __shared__ unsigned short Cs[64][68];
  __shared__ unsigned short HT[64][68];
  __shared__ float laS[64];
  const int id = blockIdx.x;
  const int h = id & 31, b = (id >> 5) & 3, c = id >> 7;
  const int tid = threadIdx.x, w = tid >> 6, lane = tid & 63;
  const int fr = lane & 15, g = lane >> 4;
  const size_t rowbase = (size_t)((b << 10) + (c << 6));
  {
    int r = tid >> 2, c0 = (tid & 3) << 4;
    const float* src = xbc + (rowbase + r) * 2176 + 2112 + c0;
    #pragma unroll
    for (int i = 0; i < 4; ++i) {
      float4 v = *(const float4*)(src + 4 * i);
      *(ushort4*)&Cs[r][c0 + 4 * i] = make_ushort4(f2bf(v.x), f2bf(v.y), f2bf(v.z), f2bf(v.w));
    }
  }
  {
    const float* hb = hseq + ((size_t)(((c << 2) + b) * 32 + h) << 12);
    int n0 = (tid & 15) << 2, p0 = (tid >> 4) << 2;
    float4 v0 = *(const float4*)(hb + ((n0 + 0) << 6) + p0);
    float4 v1 = *(const float4*)(hb + ((n0 + 1) << 6) + p0);
    float4 v2 = *(const float4*)(hb + ((n0 + 2) << 6) + p0);
    float4 v3 = *(const float4*)(hb + ((n0 + 3) << 6) + p0);
    *(ushort4*)&HT[p0 + 0][n0] = make_ushort4(f2bf(v0.x), f2bf(v1.x), f2bf(v2.x), f2bf(v3.x));
    *(ushort4*)&HT[p0 + 1][n0] = make_ushort4(f2bf(v0.y), f2bf(v1.y), f2bf(v2.y), f2bf(v3.y));
    *(ushort4*)&HT[p0 + 2][n0] = make_ushort4(f2bf(v0.z), f2bf(v1.z), f2bf(v2.z), f2bf(v3.z));
    *(ushort4*)&HT[p0 + 3][n0] = make_ushort4(f2bf(v0.w), f2bf(v1.w), f2bf(v2.w), f2bf(v3.w));
  }
  if (tid < 64) laS[tid] = labuf[(size_t)((((b << 4) | c) << 5 | h) << 6) + tid];
  __syncthreads();
  const int wr = w >> 1, wc = w & 1;
  f32x4 yf[2][2];
  #pragma unroll
  for (int i = 0; i < 2; ++i)
    #pragma unroll
    for (int j = 0; j < 2; ++j) yf[i][j] = (f32x4){0.f, 0.f, 0.f, 0.f};
  #pragma unroll
  for (int ks = 0; ks < 2; ++ks) {
    bf16x8 ca[2], hv[2];
    #pragma unroll
    for (int i = 0; i < 2; ++i) ca[i] = *(const bf16x8*)&Cs[(wr << 5) + (i << 4) + fr][(ks << 5) + (g << 3)];
    #pragma unroll
    for (int j = 0; j < 2; ++j) hv[j] = *(const bf16x8*)&HT[(wc << 5) + (j << 4) + fr][(ks << 5) + (g << 3)];
    #pragma unroll
    for (int i = 0; i < 2; ++i)
      #pragma unroll
      for (int j = 0; j < 2; ++j)
        yf[i][j] = __builtin_amdgcn_mfma_f32_16x16x32_bf16(ca[i], hv[j], yf[i][j], 0, 0, 0);
  }
  float Dh = Dv[h];
  #pragma unroll
  for (int i = 0; i < 2; ++i) {
    #pragma unroll
    for (int j = 0; j < 2; ++j) {
      int p = (wc << 5) + (j << 4) + fr;
      #pragma unroll
      for (int rr = 0; rr < 4; ++rr) {
        int t = (wr << 5) + (i << 4) + (g << 2) + rr;
        size_t yo = ((rowbase + t) << 11) + (h << 6) + p;
        float xv = xbc[(rowbase + t) * 2176 + (h << 6) + p];
        ydin[yo] = ydin[yo] + __expf(laS[t]) * yf[i][j][rr] + Dh * xv;
      }
    }
  }
}

// ---------- g = ydin * silu(z); rmsnorm(2048) * mnorm_w -> bf16 ----------
__global__ __launch_bounds__(256) void gnormk(const float* __restrict__ ydin,
    const unsigned short* __restrict__ zbf, const float* __restrict__ mw,
    unsigned short* __restrict__ gbf) {
  int row = blockIdx.x, tid = threadIdx.x;
  size_t base = ((size_t)row << 11) + ((size_t)tid << 3);
  float4 y0 = *(const float4*)(ydin + base);
  float4 y1 = *(const float4*)(ydin + base + 4);
  ushort4 z0 = *(const ushort4*)(zbf + base);
  ushort4 z1 = *(const ushort4*)(zbf + base + 4);
  float g[8];
  {
    float z;
    z = bf2f(z0.x); g[0] = y0.x * (z / (1.f + __expf(-z)));
    z = bf2f(z0.y); g[1] = y0.y * (z / (1.f + __expf(-z)));
    z = bf2f(z0.z); g[2] = y0.z * (z / (1.f + __expf(-z)));
    z = bf2f(z0.w); g[3] = y0.w * (z / (1.f + __expf(-z)));
    z = bf2f(z1.x); g[4] = y1.x * (z / (1.f + __expf(-z)));
    z = bf2f(z1.y); g[5] = y1.y * (z / (1.f + __expf(-z)));
    z = bf2f(z1.z); g[6] = y1.z * (z / (1.f + __expf(-z)));
    z = bf2f(z1.w); g[7] = y1.w * (z / (1.f + __expf(-z)));
  }
  float ss = 0.f;
  #pragma unroll
  for (int k = 0; k < 8; ++k) ss += g[k] * g[k];
  #pragma unroll
  for (int off = 32; off; off >>= 1) ss += __shfl_xor(ss, off);
  __shared__ float ws4[4];
  if ((tid & 63) == 0) ws4[tid >> 6] = ss;
  __syncthreads();
  float tot = ws4[0] + ws4[1] + ws4[2] + ws4[3];
  float sc = rsqrtf(tot * (1.f / 2048.f) + 1e-5f);
  int c0 = tid << 3;
  float4 m0 = *(const float4*)(mw + c0);
  float4 m1 = *(const float4*)(mw + c0 + 4);
  *(ushort4*)(gbf + base)     = make_ushort4(f2bf(g[0]*sc*m0.x), f2bf(g[1]*sc*m0.y), f2bf(g[2]*sc*m0.z), f2bf(g[3]*sc*m0.w));
  *(ushort4*)(gbf + base + 4) = make_ushort4(f2bf(g[4]*sc*m1.x), f2bf(g[5]*sc*m1.y), f2bf(g[6]*sc*m1.z), f2bf(g[7]*sc*m1.w));
}

// ---------- MQA causal attention (MFMA flash), out bf16 ----------
__global__ __launch_bounds__(256) void attnk(const float* __restrict__ qkv,
                                             unsigned short* __restrict__ ybf) {
  __shared__ unsigned short Qs[64][72];
  __shared__ unsigned short Ks[64][72];
  __shared__ unsigned short VT[64][72];
  __shared__ unsigned short Ps[4][16][72];
  const int id = blockIdx.x;
  const int b = id & 3, h = (id >> 2) & 15, qt = id >> 6;
  const int t0 = qt << 6;
  const int tid = threadIdx.x, w = tid >> 6, lane = tid & 63;
  const int fr = lane & 15, g = lane >> 4;
  {
    int r = tid >> 2, d0 = (tid & 3) << 4;
    const float* src = qkv + ((size_t)((b << 10) | (t0 + r))) * 1152 + (h << 6) + d0;
    #pragma unroll
    for (int i = 0; i < 4; ++i) {
      float4 v = *(const float4*)(src + 4 * i);
      *(ushort4*)&Qs[r][d0 + 4 * i] =
          make_ushort4(f2bf(v.x * 0.125f), f2bf(v.y * 0.125f), f2bf(v.z * 0.125f), f2bf(v.w * 0.125f));
    }
  }
  __syncthreads();
  bf16x8 afQ0 = *(const bf16x8*)&Qs[(w << 4) + fr][g << 3];
  bf16x8 afQ1 = *(const bf16x8*)&Qs[(w << 4) + fr][32 + (g << 3)];
  f32x4 acc_o[4];
  #pragma unroll
  for (int i = 0; i < 4; ++i) acc_o[i] = (f32x4){0.f, 0.f, 0.f, 0.f};
  float m[4] = {-1e30f, -1e30f, -1e30f, -1e30f};
  float l[4] = {0.f, 0.f, 0.f, 0.f};
  const int qrow = t0 + (w << 4) + (g << 2);
  for (int kt = 0; kt <= qt; ++kt) {
    const int s0 = kt << 6;
    __syncthreads();
    {
      int r = tid >> 2, d0 = (tid & 3) << 4;
      const float* src = qkv + ((size_t)((b << 10) | (s0 + r))) * 1152 + 1024 + d0;
      #pragma unroll
      for (int i = 0; i < 4; ++i) {
        float4 v = *(const float4*)(src + 4 * i);
        *(ushort4*)&Ks[r][d0 + 4 * i] = make_ushort4(f2bf(v.x), f2bf(v.y), f2bf(v.z), f2bf(v.w));
      }
    }
    {
      int r0 = (tid & 15) << 2, d0 = (tid >> 4) << 2;
      const float* src = qkv + ((size_t)((b << 10) | (s0 + r0))) * 1152 + 1088 + d0;
      float4 v0 = *(const float4*)(src);
      float4 v1 = *(const float4*)(src + 1152);
      float4 v2 = *(const float4*)(src + 2304);
      float4 v3 = *(const float4*)(src + 3456);
      *(ushort4*)&VT[d0 + 0][r0] = make_ushort4(f2bf(v0.x), f2bf(v1.x), f2bf(v2.x), f2bf(v3.x));
      *(ushort4*)&VT[d0 + 1][r0] = make_ushort4(f2bf(v0.y), f2bf(v1.y), f2bf(v2.y), f2bf(v3.y));
      *(ushort4*)&VT[d0 + 2][r0] = make_ushort4(f2bf(v0.z), f2bf(v1.z), f2bf(v2.z), f2bf(v3.z));
      *(ushort4*)&VT[d0 + 3][r0] = make_ushort4(f2bf(v0.w), f2bf(v1.w), f2bf(v2.w), f2bf(v3.w));
    }
    __syncthreads();
    f32x4 s4[4];
    #pragma unroll
    for (int jt = 0; jt < 4; ++jt) {
      bf16x8 b0 = *(const bf16x8*)&Ks[(jt << 4) + fr][g << 3];
      bf16x8 b1 = *(const bf16x8*)&Ks[(jt << 4) + fr][32 + (g << 3)];
      f32x4 z4 = (f32x4){0.f, 0.f, 0.f, 0.f};
      z4 = __builtin_amdgcn_mfma_f32_16x16x32_bf16(afQ0, b0, z4, 0, 0, 0);
      z4 = __builtin_amdgcn_mfma_f32_16x16x32_bf16(afQ1, b1, z4, 0, 0, 0);
      s4[jt] = z4;
    }
    if (kt == qt) {
      #pragma unroll
      for (int jt = 0; jt < 4; ++jt) {
        int key = s0 + (jt << 4) + fr;
        #pragma unroll
        for (int r = 0; r < 4; ++r)
          if (key > qrow + r) s4[jt][r] = -1e30f;
      }
    }
    #pragma unroll
    for (int r = 0; r < 4; ++r) {
      float mt = fmaxf(fmaxf(s4[0][r], s4[1][r]), fmaxf(s4[2][r], s4[3][r]));
      #pragma unroll
      for (int off = 8; off; off >>= 1) mt = fmaxf(mt, __shfl_xor(mt, off));
      float mn = fmaxf(m[r], mt);
      float scl = __expf(m[r] - mn);
      m[r] = mn;
      float ps = 0.f;
      #pragma unroll
      for (int jt = 0; jt < 4; ++jt) {
        float p = __expf(s4[jt][r] - mn);
        ps += p;
        Ps[w][(g << 2) + r][(jt << 4) + fr] = f2bf(p);
      }
      #pragma unroll
      for (int off = 8; off; off >>= 1) ps += __shfl_xor(ps, off);
      l[r] = l[r] * scl + ps;
      acc_o[0][r] *= scl; acc_o[1][r] *= scl; acc_o[2][r] *= scl; acc_o[3][r] *= scl;
    }
    #pragma unroll
    for (int ks = 0; ks < 2; ++ks) {
      bf16x8 ap = *(const bf16x8*)&Ps[w][fr][(ks << 5) + (g << 3)];
      #pragma unroll
      for (int dt = 0; dt < 4; ++dt) {
        bf16x8 bv = *(const bf16x8*)&VT[(dt << 4) + fr][(ks << 5) + (g << 3)];
        acc_o[dt] = __builtin_amdgcn_mfma_f32_16x16x32_bf16(ap, bv, acc_o[dt], 0, 0, 0);
      }
    }
  }
  #pragma unroll
  for (int dt = 0; dt < 4; ++dt) {
    #pragma unroll
    for (int r = 0; r < 4; ++r) {
      float o = acc_o[dt][r] / l[r];
      int t = t0 + (w << 4) + (g << 2) + r;
      ybf[(((size_t)((b << 10) | t)) << 10) + (h << 6) + (dt << 4) + fr] = f2bf(o);
    }
  }
}

// ---------- cmix token-shift mix -> xk, xr (bf16) ----------
__global__ __launch_bounds__(256) void mixk(const float* __restrict__ xn3,
    const float* __restrict__ tmk, const float* __restrict__ tmr,
    unsigned short* __restrict__ xkbf, unsigned short* __restrict__ xrbf) {
  int idx4 = blockIdx.x * 256 + threadIdx.x;
  int col = (idx4 & 255) << 2;
  int row = idx4 >> 8;
  int t = row & 1023;
  size_t off = ((size_t)idx4) << 2;
  float4 cur = *(const float4*)(xn3 + off);
  float4 prev = make_float4(0.f, 0.f, 0.f, 0.f);
  if (t > 0) prev = *(const float4*)(xn3 + off - 1024);
  float4 tk = *(const float4*)(tmk + col);
  float4 tr = *(const float4*)(tmr + col);
  float dx = prev.x - cur.x, dy = prev.y - cur.y, dz = prev.z - cur.z, dw = prev.w - cur.w;
  *(ushort4*)(xkbf + off) = make_ushort4(
      f2bf(cur.x + dx * tk.x), f2bf(cur.y + dy * tk.y), f2bf(cur.z + dz * tk.z), f2bf(cur.w + dw * tk.w));
  *(ushort4*)(xrbf + off) = make_ushort4(
      f2bf(cur.x + dx * tr.x), f2bf(cur.y + dy * tr.y), f2bf(cur.z + dz * tr.z), f2bf(cur.w + dw * tr.w));
}

// ---------- final: out = x2 + sigmoid(rraw) * vout ----------
__global__ __launch_bounds__(256) void finalk(const float* __restrict__ x2,
    const float* __restrict__ rraw, const float* __restrict__ vout,
    float* __restrict__ out) {
  int idx4 = blockIdx.x * 256 + threadIdx.x;
  size_t off = ((size_t)idx4) << 2;
  float4 xv = *(const float4*)(x2 + off);
  float4 rv = *(const float4*)(rraw + off);
  float4 vv = *(const float4*)(vout + off);
  float4 o;
  o.x = xv.x + vv.x / (1.f + __expf(-rv.x));
  o.y = xv.y + vv.y / (1.f + __expf(-rv.y));
  o.z = xv.z + vv.z / (1.f + __expf(-rv.z));
  o.w = xv.w + vv.w / (1.f + __expf(-rv.w));
  *(float4*)(out + off) = o;
}

// ---------- host launcher ----------
extern "C" void kernel_launch(void* const* d_in, const int* in_sizes, int n_in,
                              void* d_out, int out_size, void* d_ws, size_t ws_size,
                              hipStream_t stream) {
  (void)in_sizes; (void)n_in; (void)out_size;
  const float* x        = (const float*)d_in[0];
  const float* in_proj  = (const float*)d_in[1];
  const float* conv_w   = (const float*)d_in[2];
  const float* conv_b   = (const float*)d_in[3];
  const float* dt_bias  = (const float*)d_in[4];
  const float* A_log    = (const float*)d_in[5];
  const float* Dvec     = (const float*)d_in[6];
  const float* mnorm_w  = (const float*)d_in[7];
  const float* out_proj = (const float*)d_in[8];
  const float* attn_w   = (const float*)d_in[9];
  const float* proj_w   = (const float*)d_in[10];
  const float* tmk      = (const float*)d_in[11];
  const float* tmr      = (const float*)d_in[12];
  const float* key_w    = (const float*)d_in[13];
  const float* recept_w = (const float*)d_in[14];
  const float* value_w  = (const float*)d_in[15];
  float* out = (float*)d_out;

  if (ws_size < 199229440ull) return;

  char* ws = (char*)d_ws;
  unsigned short* Wt   = (unsigned short*)(ws + 0);
  unsigned short* Abf  = (unsigned short*)(ws + 8912896ull);
  unsigned short* Abf2 = (unsigned short*)(ws + 42467328ull);
  float* bigF = (float*)(ws + 59244544ull);
  float* big1 = (float*)(ws + 95420416ull);
  float* big2 = (float*)(ws + 131072000ull);
  float* x1   = (float*)(ws + 164626432ull);
  float* xn3  = (float*)(ws + 181403648ull);
  float* dtb  = (float*)(ws + 198180864ull);
  float* labuf= (float*)(ws + 198705152ull);
  unsigned short* zbf  = Abf2;
  unsigned short* xkbf = Abf2;
  unsigned short* xrbf = Abf2 + 4194304;
  float* dhbuf = bigF;
  float* hseq  = (float*)Abf;

  dim3 b256(256);
  dim3 b512(512);
  dim3 tb(32, 8);

  // ===== Phase A: mamba2 =====
  resrms_k<0, 0, 0><<<4096, b256, 0, stream>>>(x, nullptr, nullptr, Abf, nullptr);
  transp_k<<<dim3(64, 32), tb, 0, stream>>>(in_proj, Wt, 1024, 2048, 2048, 0, 4256);
  gemm2_k<1><<<8 * 32, b512, 0, stream>>>(Abf, Wt, zbf, 4096, 2048, 1024, 8);            // z (bf16)
  transp_k<<<dim3(72, 32), tb, 0, stream>>>(in_proj, Wt, 1024, 2208, 2304, 2048, 4256);
  gemm2_k<0><<<9 * 32, b512, 0, stream>>>(Abf, Wt, bigF, 4096, 2208, 1024, 9);           // xBC+dt (f32)
  dtk<<<512, b256, 0, stream>>>(bigF, dt_bias, dtb);
  convk<<<34816, b256, 0, stream>>>(bigF, conv_w, conv_b, big1);                         // xbc_act
  ssd1_k<<<2048, b256, 0, stream>>>(big1, dtb, A_log, big2, dhbuf, labuf);               // Y_intra, dh, la
  ssd2_k<<<2048, b256, 0, stream>>>(dhbuf, labuf, hseq);                                 // chunk states
  ssd3_k<<<2048, b256, 0, stream>>>(big1, hseq, labuf, Dvec, big2);                      // ydin final
  gnormk<<<4096, b256, 0, stream>>>(big2, zbf, mnorm_w, Abf);                            // g (bf16)
  transp_k<<<dim3(32, 64), tb, 0, stream>>>(out_proj, Wt, 2048, 1024, 1024, 0, 1024);
  gemm2_k<0><<<4 * 32, b512, 0, stream>>>(Abf, Wt, big1, 4096, 1024, 2048, 4);           // mo
  resrms_k<1, 1, 0><<<4096, b256, 0, stream>>>(x, big1, x1, Abf, nullptr);               // x1, xn2

  // ===== Phase B: mqa =====
  transp_k<<<dim3(40, 32), tb, 0, stream>>>(attn_w, Wt, 1024, 1152, 1280, 0, 1152);
  gemm2_k<0><<<5 * 32, b512, 0, stream>>>(Abf, Wt, big1, 4096, 1152, 1024, 5);           // qkv
  attnk<<<1024, b256, 0, stream>>>(big1, Abf);                                           // atty (bf16)
  transp_k<<<dim3(32, 32), tb, 0, stream>>>(proj_w, Wt, 1024, 1024, 1024, 0, 1024);
  gemm2_k<0><<<4 * 32, b512, 0, stream>>>(Abf, Wt, big2, 4096, 1024, 1024, 4);           // po
  resrms_k<1, 1, 1><<<4096, b256, 0, stream>>>(x1, big2, x1, Abf, xn3);                  // x2 (in x1), xn3

  // ===== Phase C: cmix =====
  mixk<<<4096, b256, 0, stream>>>(xn3, tmk, tmr, xkbf, xrbf);
  transp_k<<<dim3(128, 32), tb, 0, stream>>>(key_w, Wt, 1024, 4096, 4096, 0, 4096);
  gemm2_k<2><<<16 * 32, b512, 0, stream>>>(xkbf, Wt, Abf, 4096, 4096, 1024, 16);         // kact (bf16)
  transp_k<<<dim3(32, 128), tb, 0, stream>>>(value_w, Wt, 4096, 1024, 1024, 0, 1024);
  gemm2_k<0><<<4 * 32, b512, 0, stream>>>(Abf, Wt, big2, 4096, 1024, 4096, 4);           // vout
  transp_k<<<dim3(32, 32), tb, 0, stream>>>(recept_w, Wt, 1024, 1024, 1024, 0, 1024);
  gemm2_k<0><<<4 * 32, b512, 0, stream>>>(xrbf, Wt, big1, 4096, 1024, 1024, 4);          // rraw
  finalk<<<4096, b256, 0, stream>>>(x1, big1, big2, out);
}